// Round 16
// baseline (156.782 us; speedup 1.0000x reference)
//
#include <hip/hip_runtime.h>
#include <hip/hip_bf16.h>

// Problem constants
#define B_    32
#define L_    200
#define H_    256
#define NH_   4
#define D_    64
#define SCALE_ 0.125f
#define EPS_  1e-12f

typedef unsigned short u16;
typedef __attribute__((ext_vector_type(8))) short bf16x8;
typedef __attribute__((ext_vector_type(4))) short bf16x4;
typedef __attribute__((ext_vector_type(4))) float f32x4;

__device__ __forceinline__ float b2f(u16 u) {
  union { unsigned int i; float f; } v; v.i = ((unsigned int)u) << 16; return v.f;
}
__device__ __forceinline__ u16 f2b(float f) {
  union { float f; unsigned int i; } v; v.f = f;
  unsigned int u = v.i;
  return (u16)((u + 0x7FFF + ((u >> 16) & 1)) >> 16);   // RNE
}

struct PrepArgs {
  const float* X[4];     // input, pos, attr0, attr1
  const float* W[10];    // Wq,Wqp,Wqa0,Wqa1, Wk,Wka0,Wka1,Wkp, Wv, Wd
  const float* Wf1;
};
struct BiasArgs { const float* Bi[9]; };

// ---------------------------------------------------------------------------
// Kernel 0: prep — bf16 conversions, weight transposes, pad zero-fills.
// ---------------------------------------------------------------------------
__global__ __launch_bounds__(256) void prep_kernel(PrepArgs pa,
    u16* __restrict__ Xb, u16* __restrict__ Wb, u16* __restrict__ Wf1T,
    u16* __restrict__ Qb, u16* __restrict__ Kb) {
  const int N0 = 6553600, N1 = 655360, N2 = 46592, N3 = 786432, N4 = 262144;
  const int total = N0 + N1 + N2 + N3 + N4;
  for (int idx = blockIdx.x * 256 + threadIdx.x; idx < total;
       idx += gridDim.x * 256) {
    if (idx < N0) {
      int i = idx;
      int s = i / 1638400, r = i % 1638400;
      Xb[i] = f2b(pa.X[s][r]);
    } else if (idx < N0 + N1) {
      int i = idx - N0;
      int z = i >> 16, rem = i & 65535, n = rem >> 8, k = rem & 255;
      Wb[i] = f2b(pa.W[z][k * 256 + n]);
    } else if (idx < N0 + N1 + N2) {
      int i = idx - N0 - N1;
      int n = i / 224, m = i % 224;
      Wf1T[i] = (n < 200 && m < 200) ? f2b(pa.Wf1[m * 200 + n]) : (u16)0;
    } else if (idx < N0 + N1 + N2 + N3) {
      int i = idx - N0 - N1 - N2;
      int mat = i / 1536, rr = i % 1536;           // 24 rows x 64
      Qb[((size_t)mat * 224 + 200 + rr / 64) * 64 + (rr & 63)] = 0;
    } else {
      int i = idx - N0 - N1 - N2 - N3;
      int mat = i / 512, rr = i % 512;             // 8 rows x 64
      Kb[((size_t)mat * 208 + 200 + rr / 64) * 64 + (rr & 63)] = 0;
    }
  }
}

// ---------------------------------------------------------------------------
// Kernel 1: 9 projections via MFMA.  Epilogue stages the 64x256 tile in LDS
// and emits ALL needed layouts directly (transpose_kernel eliminated).
// ---------------------------------------------------------------------------
__global__ __launch_bounds__(256) void proj_mfma(
    const u16* __restrict__ Xb, const u16* __restrict__ Wb, BiasArgs ba,
    u16* __restrict__ Qb, u16* __restrict__ Kb, u16* __restrict__ Ktd,
    u16* __restrict__ Vt) {
  const int mb = blockIdx.x, z = blockIdx.y;
  const int row0 = mb * 64;
  const int tid = threadIdx.x;
  const int wv = tid >> 6, ln = tid & 63;
  const int lrow = ln & 15, lk8 = ln >> 4;

  const int zx = (z < 4) ? z : (z == 4 ? 0 : z == 5 ? 2 : z == 6 ? 3 : z == 7 ? 1 : 0);
  const u16* X  = Xb + (size_t)zx * 1638400;
  const u16* Wz = Wb + (size_t)z * 65536;
  const float* bias = ba.Bi[z];

  __shared__ u16 tile[64][264];   // pitch 264: rows 16B-aligned (528B)

  f32x4 c[4][4];
#pragma unroll
  for (int mt = 0; mt < 4; ++mt)
#pragma unroll
    for (int nt = 0; nt < 4; ++nt) c[mt][nt] = (f32x4){0.f, 0.f, 0.f, 0.f};

#pragma unroll
  for (int ks = 0; ks < 8; ++ks) {
    bf16x8 a[4], bfr[4];
#pragma unroll
    for (int mt = 0; mt < 4; ++mt)
      a[mt] = *(const bf16x8*)&X[(size_t)(row0 + mt * 16 + lrow) * 256 + ks * 32 + lk8 * 8];
#pragma unroll
    for (int nt = 0; nt < 4; ++nt)
      bfr[nt] = *(const bf16x8*)&Wz[(size_t)(wv * 64 + nt * 16 + lrow) * 256 + ks * 32 + lk8 * 8];
#pragma unroll
    for (int mt = 0; mt < 4; ++mt)
#pragma unroll
      for (int nt = 0; nt < 4; ++nt)
        c[mt][nt] = __builtin_amdgcn_mfma_f32_16x16x32_bf16(a[mt], bfr[nt], c[mt][nt], 0, 0, 0);
  }

  // stage bf16 tile in LDS
#pragma unroll
  for (int nt = 0; nt < 4; ++nt) {
    int n = wv * 64 + nt * 16 + lrow;
    float bn = bias[n];
#pragma unroll
    for (int mt = 0; mt < 4; ++mt)
#pragma unroll
      for (int j = 0; j < 4; ++j)
        tile[mt * 16 + lk8 * 4 + j][n] = f2b(c[mt][nt][j] + bn);
  }
  __syncthreads();

  if (z < 4) {
    int m = tid >> 2, h = tid & 3;
    int gm = row0 + m, b = gm / 200, l = gm - b * 200;
    u16* dst = &Qb[((size_t)((b * 4 + h) * 4 + z) * 224 + l) * 64];
    const u16* srcp = &tile[m][h * 64];
#pragma unroll
    for (int q = 0; q < 4; ++q)
      *(bf16x8*)&dst[q * 8] = *(const bf16x8*)&srcp[q * 8];
  } else if (z < 8) {
    {
      int m = tid >> 2, h = tid & 3;
      int gm = row0 + m, b = gm / 200, l = gm - b * 200;
      u16* dst = &Kb[((size_t)((b * 4 + h) * 4 + (z - 4)) * 208 + l) * 64];
      const u16* srcp = &tile[m][h * 64];
#pragma unroll
      for (int q = 0; q < 4; ++q)
        *(bf16x8*)&dst[q * 8] = *(const bf16x8*)&srcp[q * 8];
    }
    {
      int h2 = tid >> 6, d = tid & 63;
#pragma unroll
      for (int ch = 0; ch < 8; ++ch) {
        int m0c = ch * 8;
        int gmc = row0 + m0c, bc = gmc / 200, lc = gmc - bc * 200;
        int matc = (bc * 4 + h2) * 4 + (z - 4);
        bf16x8 o;
#pragma unroll
        for (int q = 0; q < 8; ++q) o[q] = (short)tile[m0c + q][h2 * 64 + d];
        *(bf16x8*)&Ktd[((size_t)matc * 64 + d) * 224 + lc] = o;
      }
    }
  } else {
    int h2 = tid >> 6, d = tid & 63;
#pragma unroll
    for (int ch = 0; ch < 8; ++ch) {
      int m0c = ch * 8;
      int gmc = row0 + m0c, bc = gmc / 200, lc = gmc - bc * 200;
      int bhc = bc * 4 + h2;
      bf16x8 o;
#pragma unroll
      for (int q = 0; q < 8; ++q) o[q] = (short)tile[m0c + q][h2 * 64 + d];
      *(bf16x8*)&Vt[((size_t)bhc * 64 + d) * 224 + lc] = o;
    }
  }
}

// ---------------------------------------------------------------------------
// Kernel 3: KW via MFMA.  (R13 config: grid 512; the grid.y=2 split of R15
// regressed — per-block fixed costs outweighed the shorter serial chain.)
// ---------------------------------------------------------------------------
__global__ __launch_bounds__(256) void kw_mfma(
    const u16* __restrict__ Wf1T, const u16* __restrict__ Ktd,
    u16* __restrict__ KWb) {
  const int mat = blockIdx.x;
  const int tid = threadIdx.x;
  const int wv = tid >> 6, ln = tid & 63;
  const int lrow = ln & 15, lk8 = ln >> 4;
  const u16* Bt = Ktd + (size_t)mat * 64 * 224;

  for (int nt = wv; nt < 13; nt += 4) {
    f32x4 cd0 = {0.f,0.f,0.f,0.f}, cd1 = {0.f,0.f,0.f,0.f};
    f32x4 cd2 = {0.f,0.f,0.f,0.f}, cd3 = {0.f,0.f,0.f,0.f};
#pragma unroll
    for (int ks = 0; ks < 7; ++ks) {
      bf16x8 a = *(const bf16x8*)&Wf1T[(size_t)(nt * 16 + lrow) * 224 + ks * 32 + lk8 * 8];
      bf16x8 b0 = *(const bf16x8*)&Bt[(size_t)(0 * 16 + lrow) * 224 + ks * 32 + lk8 * 8];
      bf16x8 b1 = *(const bf16x8*)&Bt[(size_t)(1 * 16 + lrow) * 224 + ks * 32 + lk8 * 8];
      bf16x8 b2 = *(const bf16x8*)&Bt[(size_t)(2 * 16 + lrow) * 224 + ks * 32 + lk8 * 8];
      bf16x8 b3 = *(const bf16x8*)&Bt[(size_t)(3 * 16 + lrow) * 224 + ks * 32 + lk8 * 8];
      cd0 = __builtin_amdgcn_mfma_f32_16x16x32_bf16(a, b0, cd0, 0, 0, 0);
      cd1 = __builtin_amdgcn_mfma_f32_16x16x32_bf16(a, b1, cd1, 0, 0, 0);
      cd2 = __builtin_amdgcn_mfma_f32_16x16x32_bf16(a, b2, cd2, 0, 0, 0);
      cd3 = __builtin_amdgcn_mfma_f32_16x16x32_bf16(a, b3, cd3, 0, 0, 0);
    }
#pragma unroll
    for (int j = 0; j < 4; ++j) {
      size_t base = ((size_t)mat * 256 + nt * 16 + lk8 * 4 + j) * 64 + lrow;
      KWb[base + 0]  = f2b(cd0[j]);
      KWb[base + 16] = f2b(cd1[j]);
      KWb[base + 32] = f2b(cd2[j]);
      KWb[base + 48] = f2b(cd3[j]);
    }
  }
}

// ---------------------------------------------------------------------------
// Kernel 4: fused MFMA kernel per (bh, 32-l tile), 512 THREADS (8 waves),
// 1D grid 896 with XCD-bijective swizzle.
// Energy: wave (ck=wv8&3, nh=wv8>>2) handles nt-half nh of KW panel ck ->
// serial chain 26 -> 13 iters; partials in El[2], summed at channel softmax.
// Scores: 13 m-tiles over 8 waves (<=2 each).  PV: waves 0-3 only.
// History: unroll-4 -> 240 VGPR; bounds(256,3) -> spill; LT=16 -> slower 2x.
// ---------------------------------------------------------------------------
__global__ __launch_bounds__(512) void fused_kernel(
    const u16* __restrict__ Qb, const u16* __restrict__ Kb,
    const u16* __restrict__ KWb, const u16* __restrict__ Vt,
    const float* __restrict__ mask, const float* __restrict__ bf1,
    const float* __restrict__ Wf2, u16* __restrict__ Ctxb) {
  // XCD swizzle: 896 = 8 XCDs x 112; all 7 lt-blocks of a bh share an XCD.
  const int bid = blockIdx.x;
  const int wid = (bid & 7) * 112 + (bid >> 3);
  const int lt = wid % 7, bh = wid / 7;
  const int l0 = lt * 32;
  const int b = bh >> 2, h = bh & 3;
  const int tid = threadIdx.x;
  const int wv8 = tid >> 6, ln = tid & 63;
  const int ck = wv8 & 3, nh = wv8 >> 2;
  const int lrow = ln & 15, lk8 = ln >> 4;

  __shared__ u16  qwpb[8448];        // qw [32][264] bf16, then probs [32][232]
  __shared__ float El[2][512];       // energy partials [nh][32 l][16 c]
  __shared__ float wg[512];          // channel weights
  __shared__ float b1s[256], w2s[256];
  __shared__ float redm[32][8];
  __shared__ float reds[32][8];

  if (tid < 256) {
    b1s[tid] = (tid < 200) ? bf1[tid] : 0.f;
    w2s[tid] = (tid < 200) ? Wf2[tid] : 0.f;
  }
  __syncthreads();

  // ---- phase E: energy.  wave (ck, nh): panel ck, nt in [nt0, nt1).
  {
    const u16* KWm = KWb + (size_t)(bh * 4 + ck) * 16384;
    const int nt0 = nh ? 7 : 0;
    const int nt1 = nh ? 13 : 7;
#pragma unroll
    for (int mt = 0; mt < 2; ++mt) {
      bf16x8 aE[4][2];
#pragma unroll
      for (int cq = 0; cq < 4; ++cq)
#pragma unroll
        for (int ks = 0; ks < 2; ++ks)
          aE[cq][ks] = *(const bf16x8*)&Qb[((size_t)(bh * 4 + cq) * 224 + l0 + mt * 16 + lrow) * 64 + ks * 32 + lk8 * 8];

      f32x4 eacc[4];
#pragma unroll
      for (int cq = 0; cq < 4; ++cq) eacc[cq] = (f32x4){0.f, 0.f, 0.f, 0.f};

      bf16x8 b0 = *(const bf16x8*)&KWm[(nt0 * 16 + lrow) * 64 + lk8 * 8];
      bf16x8 b1 = *(const bf16x8*)&KWm[(nt0 * 16 + lrow) * 64 + 32 + lk8 * 8];
#pragma unroll 1
      for (int nt = nt0; nt < nt1; ++nt) {
        bf16x8 nb0 = b0, nb1 = b1;
        if (nt + 1 < nt1) {
          nb0 = *(const bf16x8*)&KWm[((nt + 1) * 16 + lrow) * 64 + lk8 * 8];
          nb1 = *(const bf16x8*)&KWm[((nt + 1) * 16 + lrow) * 64 + 32 + lk8 * 8];
        }
        f32x4 c0 = {0.f, 0.f, 0.f, 0.f}, c1 = {0.f, 0.f, 0.f, 0.f};
        f32x4 c2 = {0.f, 0.f, 0.f, 0.f}, c3 = {0.f, 0.f, 0.f, 0.f};
        c0 = __builtin_amdgcn_mfma_f32_16x16x32_bf16(aE[0][0], b0, c0, 0, 0, 0);
        c1 = __builtin_amdgcn_mfma_f32_16x16x32_bf16(aE[1][0], b0, c1, 0, 0, 0);
        c2 = __builtin_amdgcn_mfma_f32_16x16x32_bf16(aE[2][0], b0, c2, 0, 0, 0);
        c3 = __builtin_amdgcn_mfma_f32_16x16x32_bf16(aE[3][0], b0, c3, 0, 0, 0);
        c0 = __builtin_amdgcn_mfma_f32_16x16x32_bf16(aE[0][1], b1, c0, 0, 0, 0);
        c1 = __builtin_amdgcn_mfma_f32_16x16x32_bf16(aE[1][1], b1, c1, 0, 0, 0);
        c2 = __builtin_amdgcn_mfma_f32_16x16x32_bf16(aE[2][1], b1, c2, 0, 0, 0);
        c3 = __builtin_amdgcn_mfma_f32_16x16x32_bf16(aE[3][1], b1, c3, 0, 0, 0);
        float b1n = b1s[nt * 16 + lrow];
        float w2n = w2s[nt * 16 + lrow];
#pragma unroll
        for (int j = 0; j < 4; ++j) {
          eacc[0][j] += fmaxf(c0[j] + b1n, 0.f) * w2n;
          eacc[1][j] += fmaxf(c1[j] + b1n, 0.f) * w2n;
          eacc[2][j] += fmaxf(c2[j] + b1n, 0.f) * w2n;
          eacc[3][j] += fmaxf(c3[j] + b1n, 0.f) * w2n;
        }
        b0 = nb0; b1 = nb1;
      }

      // reduce over 16 n-lanes; lane n=0 writes El[nh][l][cq*4+ck]
#pragma unroll
      for (int cq = 0; cq < 4; ++cq)
#pragma unroll
        for (int j = 0; j < 4; ++j) {
          float v = eacc[cq][j];
          v += __shfl_xor(v, 1);
          v += __shfl_xor(v, 2);
          v += __shfl_xor(v, 4);
          v += __shfl_xor(v, 8);
          if (lrow == 0)
            El[nh][(mt * 16 + lk8 * 4 + j) * 16 + cq * 4 + ck] = v;
        }
    }
  }
  __syncthreads();

  // ---- channel softmax over 16 c per l (512 threads: one (l,c) each)
  {
    int l = tid >> 4, c = tid & 15;
    float e = El[0][l * 16 + c] + El[1][l * 16 + c];
    float mx = e;
    mx = fmaxf(mx, __shfl_xor(mx, 8));
    mx = fmaxf(mx, __shfl_xor(mx, 4));
    mx = fmaxf(mx, __shfl_xor(mx, 2));
    mx = fmaxf(mx, __shfl_xor(mx, 1));
    float ex = __expf(e - mx);
    float s = ex;
    s += __shfl_xor(s, 8);
    s += __shfl_xor(s, 4);
    s += __shfl_xor(s, 2);
    s += __shfl_xor(s, 1);
    wg[l * 16 + c] = ex / s;
  }
  __syncthreads();

  // ---- qw[l][ck*64+d] = sum_cq w[l][cq*4+ck] * q[cq][l][d]
  // 512 threads: lq = tid>>4 (32 l), d0 = (tid&15)*4 (4 d each).
  {
    int lq = tid >> 4, d0 = (tid & 15) * 4;
    float qf[4][4];
#pragma unroll
    for (int cq = 0; cq < 4; ++cq) {
      bf16x4 q4 = *(const bf16x4*)&Qb[((size_t)(bh * 4 + cq) * 224 + l0 + lq) * 64 + d0];
#pragma unroll
      for (int j = 0; j < 4; ++j) qf[cq][j] = b2f((u16)q4[j]);
    }
    float wv_[16];
#pragma unroll
    for (int c = 0; c < 16; ++c) wv_[c] = wg[lq * 16 + c];
#pragma unroll
    for (int ck4 = 0; ck4 < 4; ++ck4) {
      float a[4];
#pragma unroll
      for (int j = 0; j < 4; ++j)
        a[j] = wv_[0 * 4 + ck4] * qf[0][j] + wv_[1 * 4 + ck4] * qf[1][j] +
               wv_[2 * 4 + ck4] * qf[2][j] + wv_[3 * 4 + ck4] * qf[3][j];
      unsigned int p0 = f2b(a[0]) | ((unsigned int)f2b(a[1]) << 16);
      unsigned int p1 = f2b(a[2]) | ((unsigned int)f2b(a[3]) << 16);
      *(unsigned int*)&qwpb[lq * 264 + ck4 * 64 + d0]     = p0;
      *(unsigned int*)&qwpb[lq * 264 + ck4 * 64 + d0 + 2] = p1;
    }
  }
  __syncthreads();

  // ---- scores into registers: wave handles m-tiles wv8, wv8+8 (mt<13)
  f32x4 s0r[2], s1r[2];
#pragma unroll
  for (int q = 0; q < 2; ++q) {
    s0r[q] = (f32x4){0.f, 0.f, 0.f, 0.f};
    s1r[q] = (f32x4){0.f, 0.f, 0.f, 0.f};
  }
#pragma unroll
  for (int q = 0; q < 2; ++q) {
    const int mt = wv8 + q * 8;
    if (mt < 13) {
      f32x4 sc0 = {0.f, 0.f, 0.f, 0.f}, sc1 = {0.f, 0.f, 0.f, 0.f};
#pragma unroll
      for (int ks = 0; ks < 8; ++ks) {
        int cks = ks >> 1, dd = (ks & 1) * 32 + lk8 * 8;
        const u16* Km = Kb + (size_t)(bh * 4 + cks) * 208 * 64;
        bf16x8 bK = *(const bf16x8*)&Km[(mt * 16 + lrow) * 64 + dd];
        bf16x8 a0 = *(const bf16x8*)&qwpb[lrow * 264 + cks * 64 + dd];
        bf16x8 a1 = *(const bf16x8*)&qwpb[(16 + lrow) * 264 + cks * 64 + dd];
        sc0 = __builtin_amdgcn_mfma_f32_16x16x32_bf16(a0, bK, sc0, 0, 0, 0);
        sc1 = __builtin_amdgcn_mfma_f32_16x16x32_bf16(a1, bK, sc1, 0, 0, 0);
      }
      s0r[q] = sc0; s1r[q] = sc1;
    }
  }

  // ---- register row-softmax.  lane's m = (wv8+8q)*16 + lrow.
  float e0[2][4], e1[2][4];
#pragma unroll
  for (int q = 0; q < 2; ++q) {
    const int mt = wv8 + q * 8;
    const int m = mt * 16 + lrow;
#pragma unroll
    for (int j = 0; j < 4; ++j) {
      if (mt < 13 && m < 200) {
        int gla = l0 + lk8 * 4 + j;      if (gla > 199) gla = 199;
        int glb = l0 + 16 + lk8 * 4 + j; if (glb > 199) glb = 199;
        e0[q][j] = s0r[q][j] * SCALE_ + mask[(size_t)gla * 200 + m];
        e1[q][j] = s1r[q][j] * SCALE_ + mask[(size_t)glb * 200 + m];
      } else {
        e0[q][j] = -3.0e38f;
        e1[q][j] = -3.0e38f;
      }
    }
  }
  float M0[4], M1[4];
#pragma unroll
  for (int j = 0; j < 4; ++j) {
    M0[j] = fmaxf(e0[0][j], e0[1][j]);
    M1[j] = fmaxf(e1[0][j], e1[1][j]);
  }
#pragma unroll
  for (int o = 8; o >= 1; o >>= 1)
#pragma unroll
    for (int j = 0; j < 4; ++j) {
      M0[j] = fmaxf(M0[j], __shfl_xor(M0[j], o));
      M1[j] = fmaxf(M1[j], __shfl_xor(M1[j], o));
    }
  if (lrow == 0) {
#pragma unroll
    for (int j = 0; j < 4; ++j) {
      redm[lk8 * 4 + j][wv8] = M0[j];
      redm[16 + lk8 * 4 + j][wv8] = M1[j];
    }
  }
  __syncthreads();
#pragma unroll
  for (int j = 0; j < 4; ++j) {
    int la = lk8 * 4 + j;
    float m0 = redm[la][0], m1 = redm[16 + la][0];
#pragma unroll
    for (int w = 1; w < 8; ++w) {
      m0 = fmaxf(m0, redm[la][w]);
      m1 = fmaxf(m1, redm[16 + la][w]);
    }
    M0[j] = m0; M1[j] = m1;
  }
  float S0[4] = {0.f, 0.f, 0.f, 0.f}, S1[4] = {0.f, 0.f, 0.f, 0.f};
#pragma unroll
  for (int q = 0; q < 2; ++q)
#pragma unroll
    for (int j = 0; j < 4; ++j) {
      e0[q][j] = __expf(e0[q][j] - M0[j]);
      e1[q][j] = __expf(e1[q][j] - M1[j]);
      S0[j] += e0[q][j];
      S1[j] += e1[q][j];
    }
#pragma unroll
  for (int o = 8; o >= 1; o >>= 1)
#pragma unroll
    for (int j = 0; j < 4; ++j) {
      S0[j] += __shfl_xor(S0[j], o);
      S1[j] += __shfl_xor(S1[j], o);
    }
  if (lrow == 0) {
#pragma unroll
    for (int j = 0; j < 4; ++j) {
      reds[lk8 * 4 + j][wv8] = S0[j];
      reds[16 + lk8 * 4 + j][wv8] = S1[j];
    }
  }
  __syncthreads();   // also: all qwpb reads (scores) complete past this point
  float R0[4], R1[4];
#pragma unroll
  for (int j = 0; j < 4; ++j) {
    int la = lk8 * 4 + j;
    float s0 = 0.f, s1v = 0.f;
#pragma unroll
    for (int w = 0; w < 8; ++w) {
      s0 += reds[la][w];
      s1v += reds[16 + la][w];
    }
    R0[j] = 1.f / s0;
    R1[j] = 1.f / s1v;
  }

  // ---- probs bf16 into pb (overlays qw region)
  u16* pb = qwpb;
  for (int idx = tid; idx < 768; idx += 512) {     // zero cols 208..231
    int l = idx / 24, mm = idx % 24;
    pb[l * 232 + 208 + mm] = 0;
  }
#pragma unroll
  for (int q = 0; q < 2; ++q) {
    const int mt = wv8 + q * 8;
    if (mt < 13) {
      const int m = mt * 16 + lrow;
#pragma unroll
      for (int j = 0; j < 4; ++j) {
        pb[(lk8 * 4 + j) * 232 + m] = f2b(e0[q][j] * R0[j]);
        pb[(16 + lk8 * 4 + j) * 232 + m] = f2b(e1[q][j] * R1[j]);
      }
    }
  }
  __syncthreads();

  // ---- PV: waves 0-3 only; wave owns d-tile wv8 (16 d).  K = 224.
  if (wv8 < 4) {
    const u16* Vb = Vt + (size_t)bh * 64 * 224;
    f32x4 pc0 = {0.f, 0.f, 0.f, 0.f}, pc1 = {0.f, 0.f, 0.f, 0.f};
#pragma unroll
    for (int ks = 0; ks < 7; ++ks) {
      int mm = ks * 32 + lk8 * 8;
      bf16x8 a0 = *(const bf16x8*)&pb[lrow * 232 + mm];
      bf16x8 a1 = *(const bf16x8*)&pb[(16 + lrow) * 232 + mm];
      bf16x8 bV = *(const bf16x8*)&Vb[(wv8 * 16 + lrow) * 224 + mm];
      pc0 = __builtin_amdgcn_mfma_f32_16x16x32_bf16(a0, bV, pc0, 0, 0, 0);
      pc1 = __builtin_amdgcn_mfma_f32_16x16x32_bf16(a1, bV, pc1, 0, 0, 0);
    }
#pragma unroll
    for (int j = 0; j < 4; ++j) {
      int la = lk8 * 4 + j, lb = 16 + lk8 * 4 + j;
      int gla = l0 + la, glb = l0 + lb;
      int d = h * 64 + wv8 * 16 + lrow;
      if (gla < 200) Ctxb[((size_t)b * 200 + gla) * 256 + d] = f2b(pc0[j]);
      if (glb < 200) Ctxb[((size_t)b * 200 + glb) * 256 + d] = f2b(pc1[j]);
    }
  }
}

// ---------------------------------------------------------------------------
// Kernel 5: out-proj via MFMA + residual + LayerNorm.  32 rows per block,
// grid 200 (R13 config; 16-row/400-block split of R15 regressed).
// ---------------------------------------------------------------------------
__global__ __launch_bounds__(256) void out_ln_kernel(
    const u16* __restrict__ Ctxb, const u16* __restrict__ WdT,
    const float* __restrict__ bd, const float* __restrict__ input,
    const float* __restrict__ gamma, const float* __restrict__ beta,
    float* __restrict__ out) {
  const int row0 = blockIdx.x * 32;
  const int tid = threadIdx.x;
  const int wv = tid >> 6, ln = tid & 63;
  const int lrow = ln & 15, lk8 = ln >> 4;

  __shared__ float redA[32][65];
  __shared__ float redB[32][65];
  __shared__ float mus[32], rsd[32];

  f32x4 c[2][4];
#pragma unroll
  for (int mt = 0; mt < 2; ++mt)
#pragma unroll
    for (int nt = 0; nt < 4; ++nt) c[mt][nt] = (f32x4){0.f, 0.f, 0.f, 0.f};

#pragma unroll
  for (int ks = 0; ks < 8; ++ks) {
    bf16x8 a[2], bfr[4];
#pragma unroll
    for (int mt = 0; mt < 2; ++mt)
      a[mt] = *(const bf16x8*)&Ctxb[(size_t)(row0 + mt * 16 + lrow) * 256 + ks * 32 + lk8 * 8];
#pragma unroll
    for (int nt = 0; nt < 4; ++nt)
      bfr[nt] = *(const bf16x8*)&WdT[(size_t)(wv * 64 + nt * 16 + lrow) * 256 + ks * 32 + lk8 * 8];
#pragma unroll
    for (int mt = 0; mt < 2; ++mt)
#pragma unroll
      for (int nt = 0; nt < 4; ++nt)
        c[mt][nt] = __builtin_amdgcn_mfma_f32_16x16x32_bf16(a[mt], bfr[nt], c[mt][nt], 0, 0, 0);
  }

  float s1[2][4], s2[2][4];
#pragma unroll
  for (int mt = 0; mt < 2; ++mt)
#pragma unroll
    for (int j = 0; j < 4; ++j) { s1[mt][j] = 0.f; s2[mt][j] = 0.f; }

#pragma unroll
  for (int nt = 0; nt < 4; ++nt) {
    int n = wv * 64 + nt * 16 + lrow;
    float bdn = bd[n];
#pragma unroll
    for (int mt = 0; mt < 2; ++mt) {
      int mbase = row0 + mt * 16 + lk8 * 4;
#pragma unroll
      for (int j = 0; j < 4; ++j) {
        float x = c[mt][nt][j] + bdn + input[(size_t)(mbase + j) * 256 + n];
        c[mt][nt][j] = x;
        s1[mt][j] += x;
        s2[mt][j] += x * x;
      }
    }
  }
#pragma unroll
  for (int mt = 0; mt < 2; ++mt)
#pragma unroll
    for (int j = 0; j < 4; ++j) {
      redA[mt * 16 + lk8 * 4 + j][wv * 16 + lrow] = s1[mt][j];
      redB[mt * 16 + lk8 * 4 + j][wv * 16 + lrow] = s2[mt][j];
    }
  __syncthreads();
  if (tid < 32) {
    float a = 0.f, b2 = 0.f;
#pragma unroll 8
    for (int i = 0; i < 64; ++i) { a += redA[tid][i]; b2 += redB[tid][i]; }
    float mu = a * (1.f / 256.f);
    float var = b2 * (1.f / 256.f) - mu * mu;
    mus[tid] = mu;
    rsd[tid] = rsqrtf(var + EPS_);
  }
  __syncthreads();
#pragma unroll
  for (int nt = 0; nt < 4; ++nt) {
    int n = wv * 64 + nt * 16 + lrow;
    float g = gamma[n], be = beta[n];
#pragma unroll
    for (int mt = 0; mt < 2; ++mt) {
#pragma unroll
      for (int j = 0; j < 4; ++j) {
        int r = mt * 16 + lk8 * 4 + j;
        out[(size_t)(row0 + r) * 256 + n] = (c[mt][nt][j] - mus[r]) * rsd[r] * g + be;
      }
    }
  }
}

// ---------------------------------------------------------------------------
extern "C" void kernel_launch(void* const* d_in, const int* in_sizes, int n_in,
                              void* d_out, int out_size, void* d_ws, size_t ws_size,
                              hipStream_t stream) {
  const float* input = (const float*)d_in[0];
  const float* attrt = (const float*)d_in[1];   // (F,B,L,1,H)
  const float* pos   = (const float*)d_in[2];
  const float* mask  = (const float*)d_in[3];
  const float* Wq  = (const float*)d_in[4];   const float* bq  = (const float*)d_in[5];
  const float* Wk  = (const float*)d_in[6];   const float* bk  = (const float*)d_in[7];
  const float* Wv  = (const float*)d_in[8];   const float* bv  = (const float*)d_in[9];
  const float* Wqp = (const float*)d_in[10];  const float* bqp = (const float*)d_in[11];
  const float* Wkp = (const float*)d_in[12];  const float* bkp = (const float*)d_in[13];
  const float* Wq_a = (const float*)d_in[16]; const float* bq_a = (const float*)d_in[17];
  const float* Wk_a = (const float*)d_in[18]; const float* bk_a = (const float*)d_in[19];
  const float* Wf1 = (const float*)d_in[22];  const float* bf1 = (const float*)d_in[23];
  const float* Wf2 = (const float*)d_in[24];
  const float* Wd  = (const float*)d_in[26];  const float* bd  = (const float*)d_in[27];
  const float* gamma = (const float*)d_in[28]; const float* beta = (const float*)d_in[29];

  const float* attr0 = attrt;
  const float* attr1 = attrt + (size_t)B_ * L_ * H_;

  u16* wsu  = (u16*)d_ws;
  u16* Xb   = wsu;                    // 6,553,600
  u16* Wb   = Xb + 6553600;           //   655,360 (10 x 256 x 256)
  u16* Wf1T = Wb + 655360;            //    46,592 (208 x 224)
  u16* Qb   = Wf1T + 46592;           // 7,340,032 (512 x 224 x 64)
  u16* Kb   = Qb + 7340032;           // 6,815,744 (512 x 208 x 64)
  u16* Ktd  = Kb + 6815744;           // 7,340,032 (512 x 64 x 224)
  u16* Vt   = Ktd + 7340032;          // 1,835,008 (128 x 64 x 224)
  u16* KWb  = Vt + 1835008;           // 8,388,608 (512 x 256 x 64)
  u16* Ctxb = KWb + 8388608;          // 1,638,400 (6400 x 256)

  PrepArgs pp;
  pp.X[0] = input; pp.X[1] = pos; pp.X[2] = attr0; pp.X[3] = attr1;
  pp.W[0] = Wq;  pp.W[1] = Wqp; pp.W[2] = Wq_a; pp.W[3] = Wq_a + 65536;
  pp.W[4] = Wk;  pp.W[5] = Wk_a; pp.W[6] = Wk_a + 65536; pp.W[7] = Wkp;
  pp.W[8] = Wv;  pp.W[9] = Wd;
  pp.Wf1 = Wf1;

  BiasArgs ba;
  ba.Bi[0] = bq;  ba.Bi[1] = bqp;  ba.Bi[2] = bq_a; ba.Bi[3] = bq_a + 256;
  ba.Bi[4] = bk;  ba.Bi[5] = bk_a; ba.Bi[6] = bk_a + 256; ba.Bi[7] = bkp;
  ba.Bi[8] = bv;

  prep_kernel<<<dim3(4096), dim3(256), 0, stream>>>(pp, Xb, Wb, Wf1T, Qb, Kb);
  proj_mfma<<<dim3(100, 9), dim3(256), 0, stream>>>(Xb, Wb, ba, Qb, Kb, Ktd, Vt);
  kw_mfma<<<dim3(512), dim3(256), 0, stream>>>(Wf1T, Ktd, KWb);
  fused_kernel<<<dim3(896), dim3(512), 0, stream>>>(Qb, Kb, KWb, Vt,
                                                    mask, bf1, Wf2, Ctxb);
  out_ln_kernel<<<dim3(200), dim3(256), 0, stream>>>(Ctxb, Wb + 9 * 65536, bd,
                                                     input, gamma, beta,
                                                     (float*)d_out);
}

// Round 17
// 138.894 us; speedup vs baseline: 1.1288x; 1.1288x over previous
//
#include <hip/hip_runtime.h>
#include <hip/hip_bf16.h>

// Problem constants
#define B_    32
#define L_    200
#define H_    256
#define NH_   4
#define D_    64
#define SCALE_ 0.125f
#define EPS_  1e-12f

typedef unsigned short u16;
typedef __attribute__((ext_vector_type(8))) short bf16x8;
typedef __attribute__((ext_vector_type(4))) float f32x4;

__device__ __forceinline__ float b2f(u16 u) {
  union { unsigned int i; float f; } v; v.i = ((unsigned int)u) << 16; return v.f;
}
__device__ __forceinline__ u16 f2b(float f) {
  union { float f; unsigned int i; } v; v.f = f;
  unsigned int u = v.i;
  return (u16)((u + 0x7FFF + ((u >> 16) & 1)) >> 16);   // RNE
}

struct PrepArgs {
  const float* X[4];     // input, pos, attr0, attr1
  const float* W[10];    // Wq,Wqp,Wqa0,Wqa1, Wk,Wka0,Wka1,Wkp, Wv, Wd
  const float* Wf1;
};
struct BiasArgs { const float* Bi[9]; };

// ---------------------------------------------------------------------------
// Kernel 0: prep — bf16 conversions, weight transposes, pad zero-fills.
// ---------------------------------------------------------------------------
__global__ __launch_bounds__(256) void prep_kernel(PrepArgs pa,
    u16* __restrict__ Xb, u16* __restrict__ Wb, u16* __restrict__ Wf1T,
    u16* __restrict__ Qb, u16* __restrict__ Kb) {
  const int N0 = 6553600, N1 = 655360, N2 = 46592, N3 = 786432, N4 = 262144;
  const int total = N0 + N1 + N2 + N3 + N4;
  for (int idx = blockIdx.x * 256 + threadIdx.x; idx < total;
       idx += gridDim.x * 256) {
    if (idx < N0) {
      int i = idx;
      int s = i / 1638400, r = i % 1638400;
      Xb[i] = f2b(pa.X[s][r]);
    } else if (idx < N0 + N1) {
      int i = idx - N0;
      int z = i >> 16, rem = i & 65535, n = rem >> 8, k = rem & 255;
      Wb[i] = f2b(pa.W[z][k * 256 + n]);
    } else if (idx < N0 + N1 + N2) {
      int i = idx - N0 - N1;
      int n = i / 224, m = i % 224;
      Wf1T[i] = (n < 200 && m < 200) ? f2b(pa.Wf1[m * 200 + n]) : (u16)0;
    } else if (idx < N0 + N1 + N2 + N3) {
      int i = idx - N0 - N1 - N2;
      int mat = i / 1536, rr = i % 1536;           // 24 rows x 64
      Qb[((size_t)mat * 224 + 200 + rr / 64) * 64 + (rr & 63)] = 0;
    } else {
      int i = idx - N0 - N1 - N2 - N3;
      int mat = i / 512, rr = i % 512;             // 8 rows x 64
      Kb[((size_t)mat * 208 + 200 + rr / 64) * 64 + (rr & 63)] = 0;
    }
  }
}

// ---------------------------------------------------------------------------
// Kernel 1: 9 projections via MFMA.  Epilogue stages the 64x256 tile in LDS
// and emits ALL needed layouts directly (transpose_kernel eliminated).
// ---------------------------------------------------------------------------
__global__ __launch_bounds__(256) void proj_mfma(
    const u16* __restrict__ Xb, const u16* __restrict__ Wb, BiasArgs ba,
    u16* __restrict__ Qb, u16* __restrict__ Kb, u16* __restrict__ Ktd,
    u16* __restrict__ Vt) {
  const int mb = blockIdx.x, z = blockIdx.y;
  const int row0 = mb * 64;
  const int tid = threadIdx.x;
  const int wv = tid >> 6, ln = tid & 63;
  const int lrow = ln & 15, lk8 = ln >> 4;

  const int zx = (z < 4) ? z : (z == 4 ? 0 : z == 5 ? 2 : z == 6 ? 3 : z == 7 ? 1 : 0);
  const u16* X  = Xb + (size_t)zx * 1638400;
  const u16* Wz = Wb + (size_t)z * 65536;
  const float* bias = ba.Bi[z];

  __shared__ u16 tile[64][264];   // pitch 264: rows 16B-aligned (528B)

  f32x4 c[4][4];
#pragma unroll
  for (int mt = 0; mt < 4; ++mt)
#pragma unroll
    for (int nt = 0; nt < 4; ++nt) c[mt][nt] = (f32x4){0.f, 0.f, 0.f, 0.f};

#pragma unroll
  for (int ks = 0; ks < 8; ++ks) {
    bf16x8 a[4], bfr[4];
#pragma unroll
    for (int mt = 0; mt < 4; ++mt)
      a[mt] = *(const bf16x8*)&X[(size_t)(row0 + mt * 16 + lrow) * 256 + ks * 32 + lk8 * 8];
#pragma unroll
    for (int nt = 0; nt < 4; ++nt)
      bfr[nt] = *(const bf16x8*)&Wz[(size_t)(wv * 64 + nt * 16 + lrow) * 256 + ks * 32 + lk8 * 8];
#pragma unroll
    for (int mt = 0; mt < 4; ++mt)
#pragma unroll
      for (int nt = 0; nt < 4; ++nt)
        c[mt][nt] = __builtin_amdgcn_mfma_f32_16x16x32_bf16(a[mt], bfr[nt], c[mt][nt], 0, 0, 0);
  }

  // stage bf16 tile in LDS
#pragma unroll
  for (int nt = 0; nt < 4; ++nt) {
    int n = wv * 64 + nt * 16 + lrow;
    float bn = bias[n];
#pragma unroll
    for (int mt = 0; mt < 4; ++mt)
#pragma unroll
      for (int j = 0; j < 4; ++j)
        tile[mt * 16 + lk8 * 4 + j][n] = f2b(c[mt][nt][j] + bn);
  }
  __syncthreads();

  if (z < 4) {
    int m = tid >> 2, h = tid & 3;
    int gm = row0 + m, b = gm / 200, l = gm - b * 200;
    u16* dst = &Qb[((size_t)((b * 4 + h) * 4 + z) * 224 + l) * 64];
    const u16* srcp = &tile[m][h * 64];
#pragma unroll
    for (int q = 0; q < 4; ++q)
      *(bf16x8*)&dst[q * 8] = *(const bf16x8*)&srcp[q * 8];
  } else if (z < 8) {
    {
      int m = tid >> 2, h = tid & 3;
      int gm = row0 + m, b = gm / 200, l = gm - b * 200;
      u16* dst = &Kb[((size_t)((b * 4 + h) * 4 + (z - 4)) * 208 + l) * 64];
      const u16* srcp = &tile[m][h * 64];
#pragma unroll
      for (int q = 0; q < 4; ++q)
        *(bf16x8*)&dst[q * 8] = *(const bf16x8*)&srcp[q * 8];
    }
    {
      int h2 = tid >> 6, d = tid & 63;
#pragma unroll
      for (int ch = 0; ch < 8; ++ch) {
        int m0c = ch * 8;
        int gmc = row0 + m0c, bc = gmc / 200, lc = gmc - bc * 200;
        int matc = (bc * 4 + h2) * 4 + (z - 4);
        bf16x8 o;
#pragma unroll
        for (int q = 0; q < 8; ++q) o[q] = (short)tile[m0c + q][h2 * 64 + d];
        *(bf16x8*)&Ktd[((size_t)matc * 64 + d) * 224 + lc] = o;
      }
    }
  } else {
    int h2 = tid >> 6, d = tid & 63;
#pragma unroll
    for (int ch = 0; ch < 8; ++ch) {
      int m0c = ch * 8;
      int gmc = row0 + m0c, bc = gmc / 200, lc = gmc - bc * 200;
      int bhc = bc * 4 + h2;
      bf16x8 o;
#pragma unroll
      for (int q = 0; q < 8; ++q) o[q] = (short)tile[m0c + q][h2 * 64 + d];
      *(bf16x8*)&Vt[((size_t)bhc * 64 + d) * 224 + lc] = o;
    }
  }
}

// ---------------------------------------------------------------------------
// Kernel 3: KW via MFMA.  (grid 512; grid.y split measured slower in R15.)
// ---------------------------------------------------------------------------
__global__ __launch_bounds__(256) void kw_mfma(
    const u16* __restrict__ Wf1T, const u16* __restrict__ Ktd,
    u16* __restrict__ KWb) {
  const int mat = blockIdx.x;
  const int tid = threadIdx.x;
  const int wv = tid >> 6, ln = tid & 63;
  const int lrow = ln & 15, lk8 = ln >> 4;
  const u16* Bt = Ktd + (size_t)mat * 64 * 224;

  for (int nt = wv; nt < 13; nt += 4) {
    f32x4 cd0 = {0.f,0.f,0.f,0.f}, cd1 = {0.f,0.f,0.f,0.f};
    f32x4 cd2 = {0.f,0.f,0.f,0.f}, cd3 = {0.f,0.f,0.f,0.f};
#pragma unroll
    for (int ks = 0; ks < 7; ++ks) {
      bf16x8 a = *(const bf16x8*)&Wf1T[(size_t)(nt * 16 + lrow) * 224 + ks * 32 + lk8 * 8];
      bf16x8 b0 = *(const bf16x8*)&Bt[(size_t)(0 * 16 + lrow) * 224 + ks * 32 + lk8 * 8];
      bf16x8 b1 = *(const bf16x8*)&Bt[(size_t)(1 * 16 + lrow) * 224 + ks * 32 + lk8 * 8];
      bf16x8 b2 = *(const bf16x8*)&Bt[(size_t)(2 * 16 + lrow) * 224 + ks * 32 + lk8 * 8];
      bf16x8 b3 = *(const bf16x8*)&Bt[(size_t)(3 * 16 + lrow) * 224 + ks * 32 + lk8 * 8];
      cd0 = __builtin_amdgcn_mfma_f32_16x16x32_bf16(a, b0, cd0, 0, 0, 0);
      cd1 = __builtin_amdgcn_mfma_f32_16x16x32_bf16(a, b1, cd1, 0, 0, 0);
      cd2 = __builtin_amdgcn_mfma_f32_16x16x32_bf16(a, b2, cd2, 0, 0, 0);
      cd3 = __builtin_amdgcn_mfma_f32_16x16x32_bf16(a, b3, cd3, 0, 0, 0);
    }
#pragma unroll
    for (int j = 0; j < 4; ++j) {
      size_t base = ((size_t)mat * 256 + nt * 16 + lk8 * 4 + j) * 64 + lrow;
      KWb[base + 0]  = f2b(cd0[j]);
      KWb[base + 16] = f2b(cd1[j]);
      KWb[base + 32] = f2b(cd2[j]);
      KWb[base + 48] = f2b(cd3[j]);
    }
  }
}

// ---------------------------------------------------------------------------
// Kernel 4: fused MFMA kernel per (bh, 32-l tile), 256 threads, grid 896
// with XCD-bijective swizzle.  energy (wave=ck) -> channel softmax -> qw ->
// scores (REGISTERS) -> register row-softmax -> probs bf16 -> PV.
// FINAL R13 config: 61.6 us, VGPR 56, LDS 24 KB, occ 33.7%.
// Probed and rejected: unroll-4 (240 VGPR), bounds(256,3) (spill),
// LT=16 (x2, slower), 8-wave split (slower).  Local optimum.
// ---------------------------------------------------------------------------
__global__ __launch_bounds__(256) void fused_kernel(
    const u16* __restrict__ Qb, const u16* __restrict__ Kb,
    const u16* __restrict__ KWb, const u16* __restrict__ Vt,
    const float* __restrict__ mask, const float* __restrict__ bf1,
    const float* __restrict__ Wf2, u16* __restrict__ Ctxb) {
  // XCD swizzle: 896 = 8 XCDs x 112; all 7 lt-blocks of a bh share an XCD.
  const int bid = blockIdx.x;
  const int wid = (bid & 7) * 112 + (bid >> 3);
  const int lt = wid % 7, bh = wid / 7;
  const int l0 = lt * 32;
  const int b = bh >> 2, h = bh & 3;
  const int tid = threadIdx.x;
  const int wv = tid >> 6, ln = tid & 63;
  const int lrow = ln & 15, lk8 = ln >> 4;

  __shared__ u16  qwpb[8448];        // qw [32][264] bf16, then probs [32][232]
  __shared__ float El[512];          // energy [32 l][16 c]
  __shared__ float wg[512];          // channel weights
  __shared__ float b1s[256], w2s[256];
  __shared__ float redm[32][4];
  __shared__ float reds[32][4];

  b1s[tid] = (tid < 200) ? bf1[tid] : 0.f;
  w2s[tid] = (tid < 200) ? Wf2[tid] : 0.f;
  __syncthreads();

  // ---- phase E: energy via MFMA.  wave wv owns ck = wv.
  {
    const u16* KWm = KWb + (size_t)(bh * 4 + wv) * 16384;
#pragma unroll
    for (int mt = 0; mt < 2; ++mt) {
      bf16x8 aE[4][2];
#pragma unroll
      for (int cq = 0; cq < 4; ++cq)
#pragma unroll
        for (int ks = 0; ks < 2; ++ks)
          aE[cq][ks] = *(const bf16x8*)&Qb[((size_t)(bh * 4 + cq) * 224 + l0 + mt * 16 + lrow) * 64 + ks * 32 + lk8 * 8];

      f32x4 eacc[4];
#pragma unroll
      for (int cq = 0; cq < 4; ++cq) eacc[cq] = (f32x4){0.f, 0.f, 0.f, 0.f};

      bf16x8 b0 = *(const bf16x8*)&KWm[lrow * 64 + lk8 * 8];
      bf16x8 b1 = *(const bf16x8*)&KWm[lrow * 64 + 32 + lk8 * 8];
#pragma unroll 1
      for (int nt = 0; nt < 13; ++nt) {
        bf16x8 nb0 = b0, nb1 = b1;
        if (nt < 12) {
          nb0 = *(const bf16x8*)&KWm[((nt + 1) * 16 + lrow) * 64 + lk8 * 8];
          nb1 = *(const bf16x8*)&KWm[((nt + 1) * 16 + lrow) * 64 + 32 + lk8 * 8];
        }
        f32x4 c0 = {0.f, 0.f, 0.f, 0.f}, c1 = {0.f, 0.f, 0.f, 0.f};
        f32x4 c2 = {0.f, 0.f, 0.f, 0.f}, c3 = {0.f, 0.f, 0.f, 0.f};
        c0 = __builtin_amdgcn_mfma_f32_16x16x32_bf16(aE[0][0], b0, c0, 0, 0, 0);
        c1 = __builtin_amdgcn_mfma_f32_16x16x32_bf16(aE[1][0], b0, c1, 0, 0, 0);
        c2 = __builtin_amdgcn_mfma_f32_16x16x32_bf16(aE[2][0], b0, c2, 0, 0, 0);
        c3 = __builtin_amdgcn_mfma_f32_16x16x32_bf16(aE[3][0], b0, c3, 0, 0, 0);
        c0 = __builtin_amdgcn_mfma_f32_16x16x32_bf16(aE[0][1], b1, c0, 0, 0, 0);
        c1 = __builtin_amdgcn_mfma_f32_16x16x32_bf16(aE[1][1], b1, c1, 0, 0, 0);
        c2 = __builtin_amdgcn_mfma_f32_16x16x32_bf16(aE[2][1], b1, c2, 0, 0, 0);
        c3 = __builtin_amdgcn_mfma_f32_16x16x32_bf16(aE[3][1], b1, c3, 0, 0, 0);
        float b1n = b1s[nt * 16 + lrow];
        float w2n = w2s[nt * 16 + lrow];
#pragma unroll
        for (int j = 0; j < 4; ++j) {
          eacc[0][j] += fmaxf(c0[j] + b1n, 0.f) * w2n;
          eacc[1][j] += fmaxf(c1[j] + b1n, 0.f) * w2n;
          eacc[2][j] += fmaxf(c2[j] + b1n, 0.f) * w2n;
          eacc[3][j] += fmaxf(c3[j] + b1n, 0.f) * w2n;
        }
        b0 = nb0; b1 = nb1;
      }

      // reduce over the 16 n-lanes; lane n=0 writes El[l][cq*4+ck]
#pragma unroll
      for (int cq = 0; cq < 4; ++cq)
#pragma unroll
        for (int j = 0; j < 4; ++j) {
          float v = eacc[cq][j];
          v += __shfl_xor(v, 1);
          v += __shfl_xor(v, 2);
          v += __shfl_xor(v, 4);
          v += __shfl_xor(v, 8);
          if (lrow == 0)
            El[(mt * 16 + lk8 * 4 + j) * 16 + cq * 4 + wv] = v;
        }
    }
  }
  __syncthreads();

  // ---- channel softmax over 16 c per l
#pragma unroll
  for (int it = 0; it < 2; ++it) {
    int l = it * 16 + (tid >> 4), c = tid & 15;
    float e = El[l * 16 + c];
    float mx = e;
    mx = fmaxf(mx, __shfl_xor(mx, 8));
    mx = fmaxf(mx, __shfl_xor(mx, 4));
    mx = fmaxf(mx, __shfl_xor(mx, 2));
    mx = fmaxf(mx, __shfl_xor(mx, 1));
    float ex = __expf(e - mx);
    float s = ex;
    s += __shfl_xor(s, 8);
    s += __shfl_xor(s, 4);
    s += __shfl_xor(s, 2);
    s += __shfl_xor(s, 1);
    wg[l * 16 + c] = ex / s;
  }
  __syncthreads();

  // ---- qw[l][ck*64+d] = sum_cq w[l][cq*4+ck] * q[cq][l][d]   (bf16, LDS)
  {
    int lq = tid >> 3, d0 = (tid & 7) * 8;
    float qf[4][8];
#pragma unroll
    for (int cq = 0; cq < 4; ++cq) {
      bf16x8 q8 = *(const bf16x8*)&Qb[((size_t)(bh * 4 + cq) * 224 + l0 + lq) * 64 + d0];
#pragma unroll
      for (int j = 0; j < 8; ++j) qf[cq][j] = b2f((u16)q8[j]);
    }
    float wv_[16];
#pragma unroll
    for (int c = 0; c < 16; ++c) wv_[c] = wg[lq * 16 + c];
#pragma unroll
    for (int ck = 0; ck < 4; ++ck) {
      float a[8];
#pragma unroll
      for (int j = 0; j < 8; ++j)
        a[j] = wv_[0 * 4 + ck] * qf[0][j] + wv_[1 * 4 + ck] * qf[1][j] +
               wv_[2 * 4 + ck] * qf[2][j] + wv_[3 * 4 + ck] * qf[3][j];
#pragma unroll
      for (int p = 0; p < 4; ++p) {
        unsigned int pk = f2b(a[2 * p]) | ((unsigned int)f2b(a[2 * p + 1]) << 16);
        *(unsigned int*)&qwpb[lq * 264 + ck * 64 + d0 + 2 * p] = pk;
      }
    }
  }
  __syncthreads();

  // ---- scores into registers: wave handles m-tiles wv+4q (q=0..3, mt<13)
  f32x4 s0r[4], s1r[4];
#pragma unroll
  for (int q = 0; q < 4; ++q) {
    s0r[q] = (f32x4){0.f, 0.f, 0.f, 0.f};
    s1r[q] = (f32x4){0.f, 0.f, 0.f, 0.f};
  }
#pragma unroll
  for (int q = 0; q < 4; ++q) {
    const int mt = wv + q * 4;
    if (mt < 13) {
      f32x4 sc0 = {0.f, 0.f, 0.f, 0.f}, sc1 = {0.f, 0.f, 0.f, 0.f};
#pragma unroll
      for (int ks = 0; ks < 8; ++ks) {
        int ck = ks >> 1, dd = (ks & 1) * 32 + lk8 * 8;
        const u16* Km = Kb + (size_t)(bh * 4 + ck) * 208 * 64;
        bf16x8 bK = *(const bf16x8*)&Km[(mt * 16 + lrow) * 64 + dd];
        bf16x8 a0 = *(const bf16x8*)&qwpb[lrow * 264 + ck * 64 + dd];
        bf16x8 a1 = *(const bf16x8*)&qwpb[(16 + lrow) * 264 + ck * 64 + dd];
        sc0 = __builtin_amdgcn_mfma_f32_16x16x32_bf16(a0, bK, sc0, 0, 0, 0);
        sc1 = __builtin_amdgcn_mfma_f32_16x16x32_bf16(a1, bK, sc1, 0, 0, 0);
      }
      s0r[q] = sc0; s1r[q] = sc1;
    }
  }

  // ---- register row-softmax.  lane's value (q,j,hh): row la=lk8*4+j (+16hh),
  // col m = (wv+4q)*16 + lrow.
  float e0[4][4], e1[4][4];
#pragma unroll
  for (int q = 0; q < 4; ++q) {
    const int mt = wv + q * 4;
    const int m = mt * 16 + lrow;
#pragma unroll
    for (int j = 0; j < 4; ++j) {
      if (mt < 13 && m < 200) {
        int gla = l0 + lk8 * 4 + j;      if (gla > 199) gla = 199;
        int glb = l0 + 16 + lk8 * 4 + j; if (glb > 199) glb = 199;
        e0[q][j] = s0r[q][j] * SCALE_ + mask[(size_t)gla * 200 + m];
        e1[q][j] = s1r[q][j] * SCALE_ + mask[(size_t)glb * 200 + m];
      } else {
        e0[q][j] = -3.0e38f;
        e1[q][j] = -3.0e38f;
      }
    }
  }
  float M0[4], M1[4];
#pragma unroll
  for (int j = 0; j < 4; ++j) {
    M0[j] = fmaxf(fmaxf(e0[0][j], e0[1][j]), fmaxf(e0[2][j], e0[3][j]));
    M1[j] = fmaxf(fmaxf(e1[0][j], e1[1][j]), fmaxf(e1[2][j], e1[3][j]));
  }
#pragma unroll
  for (int o = 8; o >= 1; o >>= 1)
#pragma unroll
    for (int j = 0; j < 4; ++j) {
      M0[j] = fmaxf(M0[j], __shfl_xor(M0[j], o));
      M1[j] = fmaxf(M1[j], __shfl_xor(M1[j], o));
    }
  if (lrow == 0) {
#pragma unroll
    for (int j = 0; j < 4; ++j) {
      redm[lk8 * 4 + j][wv] = M0[j];
      redm[16 + lk8 * 4 + j][wv] = M1[j];
    }
  }
  __syncthreads();
#pragma unroll
  for (int j = 0; j < 4; ++j) {
    int la = lk8 * 4 + j;
    M0[j] = fmaxf(fmaxf(redm[la][0], redm[la][1]), fmaxf(redm[la][2], redm[la][3]));
    M1[j] = fmaxf(fmaxf(redm[16 + la][0], redm[16 + la][1]),
                  fmaxf(redm[16 + la][2], redm[16 + la][3]));
  }
  float S0[4] = {0.f, 0.f, 0.f, 0.f}, S1[4] = {0.f, 0.f, 0.f, 0.f};
#pragma unroll
  for (int q = 0; q < 4; ++q)
#pragma unroll
    for (int j = 0; j < 4; ++j) {
      e0[q][j] = __expf(e0[q][j] - M0[j]);
      e1[q][j] = __expf(e1[q][j] - M1[j]);
      S0[j] += e0[q][j];
      S1[j] += e1[q][j];
    }
#pragma unroll
  for (int o = 8; o >= 1; o >>= 1)
#pragma unroll
    for (int j = 0; j < 4; ++j) {
      S0[j] += __shfl_xor(S0[j], o);
      S1[j] += __shfl_xor(S1[j], o);
    }
  if (lrow == 0) {
#pragma unroll
    for (int j = 0; j < 4; ++j) {
      reds[lk8 * 4 + j][wv] = S0[j];
      reds[16 + lk8 * 4 + j][wv] = S1[j];
    }
  }
  __syncthreads();   // also: all qwpb reads (scores) complete past this point
  float R0[4], R1[4];
#pragma unroll
  for (int j = 0; j < 4; ++j) {
    int la = lk8 * 4 + j;
    R0[j] = 1.f / (reds[la][0] + reds[la][1] + reds[la][2] + reds[la][3]);
    R1[j] = 1.f / (reds[16 + la][0] + reds[16 + la][1] +
                   reds[16 + la][2] + reds[16 + la][3]);
  }

  // ---- probs bf16 into pb (overlays qw region)
  u16* pb = qwpb;
  for (int idx = tid; idx < 768; idx += 256) {     // zero cols 208..231
    int l = idx / 24, mm = idx % 24;
    pb[l * 232 + 208 + mm] = 0;
  }
#pragma unroll
  for (int q = 0; q < 4; ++q) {
    const int mt = wv + q * 4;
    if (mt < 13) {
      const int m = mt * 16 + lrow;
#pragma unroll
      for (int j = 0; j < 4; ++j) {
        pb[(lk8 * 4 + j) * 232 + m] = f2b(e0[q][j] * R0[j]);
        pb[(16 + lk8 * 4 + j) * 232 + m] = f2b(e1[q][j] * R1[j]);
      }
    }
  }
  __syncthreads();

  // ---- PV: wave owns d-tile wv (16 d).  K = 224 (7 steps), pad probs = 0.
  {
    const u16* Vb = Vt + (size_t)bh * 64 * 224;
    f32x4 pc0 = {0.f, 0.f, 0.f, 0.f}, pc1 = {0.f, 0.f, 0.f, 0.f};
#pragma unroll
    for (int ks = 0; ks < 7; ++ks) {
      int mm = ks * 32 + lk8 * 8;
      bf16x8 a0 = *(const bf16x8*)&pb[lrow * 232 + mm];
      bf16x8 a1 = *(const bf16x8*)&pb[(16 + lrow) * 232 + mm];
      bf16x8 bV = *(const bf16x8*)&Vb[(wv * 16 + lrow) * 224 + mm];
      pc0 = __builtin_amdgcn_mfma_f32_16x16x32_bf16(a0, bV, pc0, 0, 0, 0);
      pc1 = __builtin_amdgcn_mfma_f32_16x16x32_bf16(a1, bV, pc1, 0, 0, 0);
    }
#pragma unroll
    for (int j = 0; j < 4; ++j) {
      int la = lk8 * 4 + j, lb = 16 + lk8 * 4 + j;
      int gla = l0 + la, glb = l0 + lb;
      int d = h * 64 + wv * 16 + lrow;
      if (gla < 200) Ctxb[((size_t)b * 200 + gla) * 256 + d] = f2b(pc0[j]);
      if (glb < 200) Ctxb[((size_t)b * 200 + glb) * 256 + d] = f2b(pc1[j]);
    }
  }
}

// ---------------------------------------------------------------------------
// Kernel 5: out-proj via MFMA + residual + LayerNorm.  32 rows per block,
// grid 200 (R13 config; 16-row/400-block split measured slower in R15).
// ---------------------------------------------------------------------------
__global__ __launch_bounds__(256) void out_ln_kernel(
    const u16* __restrict__ Ctxb, const u16* __restrict__ WdT,
    const float* __restrict__ bd, const float* __restrict__ input,
    const float* __restrict__ gamma, const float* __restrict__ beta,
    float* __restrict__ out) {
  const int row0 = blockIdx.x * 32;
  const int tid = threadIdx.x;
  const int wv = tid >> 6, ln = tid & 63;
  const int lrow = ln & 15, lk8 = ln >> 4;

  __shared__ float redA[32][65];
  __shared__ float redB[32][65];
  __shared__ float mus[32], rsd[32];

  f32x4 c[2][4];
#pragma unroll
  for (int mt = 0; mt < 2; ++mt)
#pragma unroll
    for (int nt = 0; nt < 4; ++nt) c[mt][nt] = (f32x4){0.f, 0.f, 0.f, 0.f};

#pragma unroll
  for (int ks = 0; ks < 8; ++ks) {
    bf16x8 a[2], bfr[4];
#pragma unroll
    for (int mt = 0; mt < 2; ++mt)
      a[mt] = *(const bf16x8*)&Ctxb[(size_t)(row0 + mt * 16 + lrow) * 256 + ks * 32 + lk8 * 8];
#pragma unroll
    for (int nt = 0; nt < 4; ++nt)
      bfr[nt] = *(const bf16x8*)&WdT[(size_t)(wv * 64 + nt * 16 + lrow) * 256 + ks * 32 + lk8 * 8];
#pragma unroll
    for (int mt = 0; mt < 2; ++mt)
#pragma unroll
      for (int nt = 0; nt < 4; ++nt)
        c[mt][nt] = __builtin_amdgcn_mfma_f32_16x16x32_bf16(a[mt], bfr[nt], c[mt][nt], 0, 0, 0);
  }

  float s1[2][4], s2[2][4];
#pragma unroll
  for (int mt = 0; mt < 2; ++mt)
#pragma unroll
    for (int j = 0; j < 4; ++j) { s1[mt][j] = 0.f; s2[mt][j] = 0.f; }

#pragma unroll
  for (int nt = 0; nt < 4; ++nt) {
    int n = wv * 64 + nt * 16 + lrow;
    float bdn = bd[n];
#pragma unroll
    for (int mt = 0; mt < 2; ++mt) {
      int mbase = row0 + mt * 16 + lk8 * 4;
#pragma unroll
      for (int j = 0; j < 4; ++j) {
        float x = c[mt][nt][j] + bdn + input[(size_t)(mbase + j) * 256 + n];
        c[mt][nt][j] = x;
        s1[mt][j] += x;
        s2[mt][j] += x * x;
      }
    }
  }
#pragma unroll
  for (int mt = 0; mt < 2; ++mt)
#pragma unroll
    for (int j = 0; j < 4; ++j) {
      redA[mt * 16 + lk8 * 4 + j][wv * 16 + lrow] = s1[mt][j];
      redB[mt * 16 + lk8 * 4 + j][wv * 16 + lrow] = s2[mt][j];
    }
  __syncthreads();
  if (tid < 32) {
    float a = 0.f, b2 = 0.f;
#pragma unroll 8
    for (int i = 0; i < 64; ++i) { a += redA[tid][i]; b2 += redB[tid][i]; }
    float mu = a * (1.f / 256.f);
    float var = b2 * (1.f / 256.f) - mu * mu;
    mus[tid] = mu;
    rsd[tid] = rsqrtf(var + EPS_);
  }
  __syncthreads();
#pragma unroll
  for (int nt = 0; nt < 4; ++nt) {
    int n = wv * 64 + nt * 16 + lrow;
    float g = gamma[n], be = beta[n];
#pragma unroll
    for (int mt = 0; mt < 2; ++mt) {
#pragma unroll
      for (int j = 0; j < 4; ++j) {
        int r = mt * 16 + lk8 * 4 + j;
        out[(size_t)(row0 + r) * 256 + n] = (c[mt][nt][j] - mus[r]) * rsd[r] * g + be;
      }
    }
  }
}

// ---------------------------------------------------------------------------
extern "C" void kernel_launch(void* const* d_in, const int* in_sizes, int n_in,
                              void* d_out, int out_size, void* d_ws, size_t ws_size,
                              hipStream_t stream) {
  const float* input = (const float*)d_in[0];
  const float* attrt = (const float*)d_in[1];   // (F,B,L,1,H)
  const float* pos   = (const float*)d_in[2];
  const float* mask  = (const float*)d_in[3];
  const float* Wq  = (const float*)d_in[4];   const float* bq  = (const float*)d_in[5];
  const float* Wk  = (const float*)d_in[6];   const float* bk  = (const float*)d_in[7];
  const float* Wv  = (const float*)d_in[8];   const float* bv  = (const float*)d_in[9];
  const float* Wqp = (const float*)d_in[10];  const float* bqp = (const float*)d_in[11];
  const float* Wkp = (const float*)d_in[12];  const float* bkp = (const float*)d_in[13];
  const float* Wq_a = (const float*)d_in[16]; const float* bq_a = (const float*)d_in[17];
  const float* Wk_a = (const float*)d_in[18]; const float* bk_a = (const float*)d_in[19];
  const float* Wf1 = (const float*)d_in[22];  const float* bf1 = (const float*)d_in[23];
  const float* Wf2 = (const float*)d_in[24];
  const float* Wd  = (const float*)d_in[26];  const float* bd  = (const float*)d_in[27];
  const float* gamma = (const float*)d_in[28]; const float* beta = (const float*)d_in[29];

  const float* attr0 = attrt;
  const float* attr1 = attrt + (size_t)B_ * L_ * H_;

  u16* wsu  = (u16*)d_ws;
  u16* Xb   = wsu;                    // 6,553,600
  u16* Wb   = Xb + 6553600;           //   655,360 (10 x 256 x 256)
  u16* Wf1T = Wb + 655360;            //    46,592 (208 x 224)
  u16* Qb   = Wf1T + 46592;           // 7,340,032 (512 x 224 x 64)
  u16* Kb   = Qb + 7340032;           // 6,815,744 (512 x 208 x 64)
  u16* Ktd  = Kb + 6815744;           // 7,340,032 (512 x 64 x 224)
  u16* Vt   = Ktd + 7340032;          // 1,835,008 (128 x 64 x 224)
  u16* KWb  = Vt + 1835008;           // 8,388,608 (512 x 256 x 64)
  u16* Ctxb = KWb + 8388608;          // 1,638,400 (6400 x 256)

  PrepArgs pp;
  pp.X[0] = input; pp.X[1] = pos; pp.X[2] = attr0; pp.X[3] = attr1;
  pp.W[0] = Wq;  pp.W[1] = Wqp; pp.W[2] = Wq_a; pp.W[3] = Wq_a + 65536;
  pp.W[4] = Wk;  pp.W[5] = Wk_a; pp.W[6] = Wk_a + 65536; pp.W[7] = Wkp;
  pp.W[8] = Wv;  pp.W[9] = Wd;
  pp.Wf1 = Wf1;

  BiasArgs ba;
  ba.Bi[0] = bq;  ba.Bi[1] = bqp;  ba.Bi[2] = bq_a; ba.Bi[3] = bq_a + 256;
  ba.Bi[4] = bk;  ba.Bi[5] = bk_a; ba.Bi[6] = bk_a + 256; ba.Bi[7] = bkp;
  ba.Bi[8] = bv;

  prep_kernel<<<dim3(4096), dim3(256), 0, stream>>>(pp, Xb, Wb, Wf1T, Qb, Kb);
  proj_mfma<<<dim3(100, 9), dim3(256), 0, stream>>>(Xb, Wb, ba, Qb, Kb, Ktd, Vt);
  kw_mfma<<<dim3(512), dim3(256), 0, stream>>>(Wf1T, Ktd, KWb);
  fused_kernel<<<dim3(896), dim3(256), 0, stream>>>(Qb, Kb, KWb, Vt,
                                                    mask, bf1, Wf2, Ctxb);
  out_ln_kernel<<<dim3(200), dim3(256), 0, stream>>>(Ctxb, Wb + 9 * 65536, bd,
                                                     input, gamma, beta,
                                                     (float*)d_out);
}

// Round 18
// 136.773 us; speedup vs baseline: 1.1463x; 1.0155x over previous
//
#include <hip/hip_runtime.h>
#include <hip/hip_bf16.h>

// Problem constants
#define B_    32
#define L_    200
#define H_    256
#define NH_   4
#define D_    64
#define SCALE_ 0.125f
#define EPS_  1e-12f

typedef unsigned short u16;
typedef __attribute__((ext_vector_type(8))) short bf16x8;
typedef __attribute__((ext_vector_type(4))) float f32x4;

__device__ __forceinline__ float b2f(u16 u) {
  union { unsigned int i; float f; } v; v.i = ((unsigned int)u) << 16; return v.f;
}
__device__ __forceinline__ u16 f2b(float f) {
  union { float f; unsigned int i; } v; v.f = f;
  unsigned int u = v.i;
  return (u16)((u + 0x7FFF + ((u >> 16) & 1)) >> 16);   // RNE
}

struct PrepArgs {
  const float* X[4];     // input, pos, attr0, attr1
  const float* W[10];    // Wq,Wqp,Wqa0,Wqa1, Wk,Wka0,Wka1,Wkp, Wv, Wd
  const float* Wf1;
};
struct BiasArgs { const float* Bi[9]; };

// ---------------------------------------------------------------------------
// Kernel 0: prep — bf16 conversions, weight transposes, pad zero-fills.
// Xb segment and zero-fills vectorized x4 (G13); strided W transposes scalar.
// Segment sizes all %4==0, so 4-element groups never straddle a boundary.
// ---------------------------------------------------------------------------
__global__ __launch_bounds__(256) void prep_kernel(PrepArgs pa,
    u16* __restrict__ Xb, u16* __restrict__ Wb, u16* __restrict__ Wf1T,
    u16* __restrict__ Qb, u16* __restrict__ Kb) {
  const int G0 = 1638400;              // Xb: 6,553,600 / 4 groups
  const int G1 = G0 + 655360;          // Wb: scalar (stride-256 source reads)
  const int G2 = G1 + 46592;           // Wf1T: scalar (stride-200 source reads)
  const int G3 = G2 + 196608;          // Qb zero-fill: 786,432 / 4
  const int G4 = G3 + 65536;           // Kb zero-fill: 262,144 / 4
  for (int idx = blockIdx.x * 256 + threadIdx.x; idx < G4;
       idx += gridDim.x * 256) {
    if (idx < G0) {
      int i = idx * 4;
      int s = i / 1638400, r = i - s * 1638400;     // same s for all 4 elems
      float4 v = *(const float4*)&pa.X[s][r];
      unsigned int p0 = f2b(v.x) | ((unsigned int)f2b(v.y) << 16);
      unsigned int p1 = f2b(v.z) | ((unsigned int)f2b(v.w) << 16);
      *(unsigned int*)&Xb[i]     = p0;
      *(unsigned int*)&Xb[i + 2] = p1;
    } else if (idx < G1) {
      int i = idx - G0;
      int z = i >> 16, rem = i & 65535, n = rem >> 8, k = rem & 255;
      Wb[i] = f2b(pa.W[z][k * 256 + n]);
    } else if (idx < G2) {
      int i = idx - G1;
      int n = i / 224, m = i % 224;
      Wf1T[i] = (n < 200 && m < 200) ? f2b(pa.Wf1[m * 200 + n]) : (u16)0;
    } else if (idx < G3) {
      int i = (idx - G2) * 4;
      int mat = i / 1536, rr = i - mat * 1536;      // 24 rows x 64, col%4==0
      u16* dst = &Qb[((size_t)mat * 224 + 200 + rr / 64) * 64 + (rr & 63)];
      *(unsigned int*)&dst[0] = 0u;
      *(unsigned int*)&dst[2] = 0u;
    } else {
      int i = (idx - G3) * 4;
      int mat = i / 512, rr = i - mat * 512;        // 8 rows x 64
      u16* dst = &Kb[((size_t)mat * 208 + 200 + rr / 64) * 64 + (rr & 63)];
      *(unsigned int*)&dst[0] = 0u;
      *(unsigned int*)&dst[2] = 0u;
    }
  }
}

// ---------------------------------------------------------------------------
// Kernel 1: 9 projections via MFMA.  Epilogue stages the 64x256 tile in LDS
// and emits ALL needed layouts directly (transpose_kernel eliminated).
// ---------------------------------------------------------------------------
__global__ __launch_bounds__(256) void proj_mfma(
    const u16* __restrict__ Xb, const u16* __restrict__ Wb, BiasArgs ba,
    u16* __restrict__ Qb, u16* __restrict__ Kb, u16* __restrict__ Ktd,
    u16* __restrict__ Vt) {
  const int mb = blockIdx.x, z = blockIdx.y;
  const int row0 = mb * 64;
  const int tid = threadIdx.x;
  const int wv = tid >> 6, ln = tid & 63;
  const int lrow = ln & 15, lk8 = ln >> 4;

  const int zx = (z < 4) ? z : (z == 4 ? 0 : z == 5 ? 2 : z == 6 ? 3 : z == 7 ? 1 : 0);
  const u16* X  = Xb + (size_t)zx * 1638400;
  const u16* Wz = Wb + (size_t)z * 65536;
  const float* bias = ba.Bi[z];

  __shared__ u16 tile[64][264];   // pitch 264: rows 16B-aligned (528B)

  f32x4 c[4][4];
#pragma unroll
  for (int mt = 0; mt < 4; ++mt)
#pragma unroll
    for (int nt = 0; nt < 4; ++nt) c[mt][nt] = (f32x4){0.f, 0.f, 0.f, 0.f};

#pragma unroll
  for (int ks = 0; ks < 8; ++ks) {
    bf16x8 a[4], bfr[4];
#pragma unroll
    for (int mt = 0; mt < 4; ++mt)
      a[mt] = *(const bf16x8*)&X[(size_t)(row0 + mt * 16 + lrow) * 256 + ks * 32 + lk8 * 8];
#pragma unroll
    for (int nt = 0; nt < 4; ++nt)
      bfr[nt] = *(const bf16x8*)&Wz[(size_t)(wv * 64 + nt * 16 + lrow) * 256 + ks * 32 + lk8 * 8];
#pragma unroll
    for (int mt = 0; mt < 4; ++mt)
#pragma unroll
      for (int nt = 0; nt < 4; ++nt)
        c[mt][nt] = __builtin_amdgcn_mfma_f32_16x16x32_bf16(a[mt], bfr[nt], c[mt][nt], 0, 0, 0);
  }

  // stage bf16 tile in LDS
#pragma unroll
  for (int nt = 0; nt < 4; ++nt) {
    int n = wv * 64 + nt * 16 + lrow;
    float bn = bias[n];
#pragma unroll
    for (int mt = 0; mt < 4; ++mt)
#pragma unroll
      for (int j = 0; j < 4; ++j)
        tile[mt * 16 + lk8 * 4 + j][n] = f2b(c[mt][nt][j] + bn);
  }
  __syncthreads();

  if (z < 4) {
    int m = tid >> 2, h = tid & 3;
    int gm = row0 + m, b = gm / 200, l = gm - b * 200;
    u16* dst = &Qb[((size_t)((b * 4 + h) * 4 + z) * 224 + l) * 64];
    const u16* srcp = &tile[m][h * 64];
#pragma unroll
    for (int q = 0; q < 4; ++q)
      *(bf16x8*)&dst[q * 8] = *(const bf16x8*)&srcp[q * 8];
  } else if (z < 8) {
    {
      int m = tid >> 2, h = tid & 3;
      int gm = row0 + m, b = gm / 200, l = gm - b * 200;
      u16* dst = &Kb[((size_t)((b * 4 + h) * 4 + (z - 4)) * 208 + l) * 64];
      const u16* srcp = &tile[m][h * 64];
#pragma unroll
      for (int q = 0; q < 4; ++q)
        *(bf16x8*)&dst[q * 8] = *(const bf16x8*)&srcp[q * 8];
    }
    {
      int h2 = tid >> 6, d = tid & 63;
#pragma unroll
      for (int ch = 0; ch < 8; ++ch) {
        int m0c = ch * 8;
        int gmc = row0 + m0c, bc = gmc / 200, lc = gmc - bc * 200;
        int matc = (bc * 4 + h2) * 4 + (z - 4);
        bf16x8 o;
#pragma unroll
        for (int q = 0; q < 8; ++q) o[q] = (short)tile[m0c + q][h2 * 64 + d];
        *(bf16x8*)&Ktd[((size_t)matc * 64 + d) * 224 + lc] = o;
      }
    }
  } else {
    int h2 = tid >> 6, d = tid & 63;
#pragma unroll
    for (int ch = 0; ch < 8; ++ch) {
      int m0c = ch * 8;
      int gmc = row0 + m0c, bc = gmc / 200, lc = gmc - bc * 200;
      int bhc = bc * 4 + h2;
      bf16x8 o;
#pragma unroll
      for (int q = 0; q < 8; ++q) o[q] = (short)tile[m0c + q][h2 * 64 + d];
      *(bf16x8*)&Vt[((size_t)bhc * 64 + d) * 224 + lc] = o;
    }
  }
}

// ---------------------------------------------------------------------------
// Kernel 3: KW via MFMA.  (grid 512; grid.y split measured slower in R15.)
// ---------------------------------------------------------------------------
__global__ __launch_bounds__(256) void kw_mfma(
    const u16* __restrict__ Wf1T, const u16* __restrict__ Ktd,
    u16* __restrict__ KWb) {
  const int mat = blockIdx.x;
  const int tid = threadIdx.x;
  const int wv = tid >> 6, ln = tid & 63;
  const int lrow = ln & 15, lk8 = ln >> 4;
  const u16* Bt = Ktd + (size_t)mat * 64 * 224;

  for (int nt = wv; nt < 13; nt += 4) {
    f32x4 cd0 = {0.f,0.f,0.f,0.f}, cd1 = {0.f,0.f,0.f,0.f};
    f32x4 cd2 = {0.f,0.f,0.f,0.f}, cd3 = {0.f,0.f,0.f,0.f};
#pragma unroll
    for (int ks = 0; ks < 7; ++ks) {
      bf16x8 a = *(const bf16x8*)&Wf1T[(size_t)(nt * 16 + lrow) * 224 + ks * 32 + lk8 * 8];
      bf16x8 b0 = *(const bf16x8*)&Bt[(size_t)(0 * 16 + lrow) * 224 + ks * 32 + lk8 * 8];
      bf16x8 b1 = *(const bf16x8*)&Bt[(size_t)(1 * 16 + lrow) * 224 + ks * 32 + lk8 * 8];
      bf16x8 b2 = *(const bf16x8*)&Bt[(size_t)(2 * 16 + lrow) * 224 + ks * 32 + lk8 * 8];
      bf16x8 b3 = *(const bf16x8*)&Bt[(size_t)(3 * 16 + lrow) * 224 + ks * 32 + lk8 * 8];
      cd0 = __builtin_amdgcn_mfma_f32_16x16x32_bf16(a, b0, cd0, 0, 0, 0);
      cd1 = __builtin_amdgcn_mfma_f32_16x16x32_bf16(a, b1, cd1, 0, 0, 0);
      cd2 = __builtin_amdgcn_mfma_f32_16x16x32_bf16(a, b2, cd2, 0, 0, 0);
      cd3 = __builtin_amdgcn_mfma_f32_16x16x32_bf16(a, b3, cd3, 0, 0, 0);
    }
#pragma unroll
    for (int j = 0; j < 4; ++j) {
      size_t base = ((size_t)mat * 256 + nt * 16 + lk8 * 4 + j) * 64 + lrow;
      KWb[base + 0]  = f2b(cd0[j]);
      KWb[base + 16] = f2b(cd1[j]);
      KWb[base + 32] = f2b(cd2[j]);
      KWb[base + 48] = f2b(cd3[j]);
    }
  }
}

// ---------------------------------------------------------------------------
// Kernel 4: fused MFMA kernel per (bh, 32-l tile), 256 threads, grid 896
// with XCD-bijective swizzle.  energy (wave=ck) -> channel softmax -> qw ->
// scores (REGISTERS) -> register row-softmax -> probs bf16 -> PV.
// FINAL R13 config: 61.6 us, VGPR 56, LDS 24 KB, occ 33.7%.  FROZEN.
// ---------------------------------------------------------------------------
__global__ __launch_bounds__(256) void fused_kernel(
    const u16* __restrict__ Qb, const u16* __restrict__ Kb,
    const u16* __restrict__ KWb, const u16* __restrict__ Vt,
    const float* __restrict__ mask, const float* __restrict__ bf1,
    const float* __restrict__ Wf2, u16* __restrict__ Ctxb) {
  // XCD swizzle: 896 = 8 XCDs x 112; all 7 lt-blocks of a bh share an XCD.
  const int bid = blockIdx.x;
  const int wid = (bid & 7) * 112 + (bid >> 3);
  const int lt = wid % 7, bh = wid / 7;
  const int l0 = lt * 32;
  const int b = bh >> 2, h = bh & 3;
  const int tid = threadIdx.x;
  const int wv = tid >> 6, ln = tid & 63;
  const int lrow = ln & 15, lk8 = ln >> 4;

  __shared__ u16  qwpb[8448];        // qw [32][264] bf16, then probs [32][232]
  __shared__ float El[512];          // energy [32 l][16 c]
  __shared__ float wg[512];          // channel weights
  __shared__ float b1s[256], w2s[256];
  __shared__ float redm[32][4];
  __shared__ float reds[32][4];

  b1s[tid] = (tid < 200) ? bf1[tid] : 0.f;
  w2s[tid] = (tid < 200) ? Wf2[tid] : 0.f;
  __syncthreads();

  // ---- phase E: energy via MFMA.  wave wv owns ck = wv.
  {
    const u16* KWm = KWb + (size_t)(bh * 4 + wv) * 16384;
#pragma unroll
    for (int mt = 0; mt < 2; ++mt) {
      bf16x8 aE[4][2];
#pragma unroll
      for (int cq = 0; cq < 4; ++cq)
#pragma unroll
        for (int ks = 0; ks < 2; ++ks)
          aE[cq][ks] = *(const bf16x8*)&Qb[((size_t)(bh * 4 + cq) * 224 + l0 + mt * 16 + lrow) * 64 + ks * 32 + lk8 * 8];

      f32x4 eacc[4];
#pragma unroll
      for (int cq = 0; cq < 4; ++cq) eacc[cq] = (f32x4){0.f, 0.f, 0.f, 0.f};

      bf16x8 b0 = *(const bf16x8*)&KWm[lrow * 64 + lk8 * 8];
      bf16x8 b1 = *(const bf16x8*)&KWm[lrow * 64 + 32 + lk8 * 8];
#pragma unroll 1
      for (int nt = 0; nt < 13; ++nt) {
        bf16x8 nb0 = b0, nb1 = b1;
        if (nt < 12) {
          nb0 = *(const bf16x8*)&KWm[((nt + 1) * 16 + lrow) * 64 + lk8 * 8];
          nb1 = *(const bf16x8*)&KWm[((nt + 1) * 16 + lrow) * 64 + 32 + lk8 * 8];
        }
        f32x4 c0 = {0.f, 0.f, 0.f, 0.f}, c1 = {0.f, 0.f, 0.f, 0.f};
        f32x4 c2 = {0.f, 0.f, 0.f, 0.f}, c3 = {0.f, 0.f, 0.f, 0.f};
        c0 = __builtin_amdgcn_mfma_f32_16x16x32_bf16(aE[0][0], b0, c0, 0, 0, 0);
        c1 = __builtin_amdgcn_mfma_f32_16x16x32_bf16(aE[1][0], b0, c1, 0, 0, 0);
        c2 = __builtin_amdgcn_mfma_f32_16x16x32_bf16(aE[2][0], b0, c2, 0, 0, 0);
        c3 = __builtin_amdgcn_mfma_f32_16x16x32_bf16(aE[3][0], b0, c3, 0, 0, 0);
        c0 = __builtin_amdgcn_mfma_f32_16x16x32_bf16(aE[0][1], b1, c0, 0, 0, 0);
        c1 = __builtin_amdgcn_mfma_f32_16x16x32_bf16(aE[1][1], b1, c1, 0, 0, 0);
        c2 = __builtin_amdgcn_mfma_f32_16x16x32_bf16(aE[2][1], b1, c2, 0, 0, 0);
        c3 = __builtin_amdgcn_mfma_f32_16x16x32_bf16(aE[3][1], b1, c3, 0, 0, 0);
        float b1n = b1s[nt * 16 + lrow];
        float w2n = w2s[nt * 16 + lrow];
#pragma unroll
        for (int j = 0; j < 4; ++j) {
          eacc[0][j] += fmaxf(c0[j] + b1n, 0.f) * w2n;
          eacc[1][j] += fmaxf(c1[j] + b1n, 0.f) * w2n;
          eacc[2][j] += fmaxf(c2[j] + b1n, 0.f) * w2n;
          eacc[3][j] += fmaxf(c3[j] + b1n, 0.f) * w2n;
        }
        b0 = nb0; b1 = nb1;
      }

      // reduce over the 16 n-lanes; lane n=0 writes El[l][cq*4+ck]
#pragma unroll
      for (int cq = 0; cq < 4; ++cq)
#pragma unroll
        for (int j = 0; j < 4; ++j) {
          float v = eacc[cq][j];
          v += __shfl_xor(v, 1);
          v += __shfl_xor(v, 2);
          v += __shfl_xor(v, 4);
          v += __shfl_xor(v, 8);
          if (lrow == 0)
            El[(mt * 16 + lk8 * 4 + j) * 16 + cq * 4 + wv] = v;
        }
    }
  }
  __syncthreads();

  // ---- channel softmax over 16 c per l
#pragma unroll
  for (int it = 0; it < 2; ++it) {
    int l = it * 16 + (tid >> 4), c = tid & 15;
    float e = El[l * 16 + c];
    float mx = e;
    mx = fmaxf(mx, __shfl_xor(mx, 8));
    mx = fmaxf(mx, __shfl_xor(mx, 4));
    mx = fmaxf(mx, __shfl_xor(mx, 2));
    mx = fmaxf(mx, __shfl_xor(mx, 1));
    float ex = __expf(e - mx);
    float s = ex;
    s += __shfl_xor(s, 8);
    s += __shfl_xor(s, 4);
    s += __shfl_xor(s, 2);
    s += __shfl_xor(s, 1);
    wg[l * 16 + c] = ex / s;
  }
  __syncthreads();

  // ---- qw[l][ck*64+d] = sum_cq w[l][cq*4+ck] * q[cq][l][d]   (bf16, LDS)
  {
    int lq = tid >> 3, d0 = (tid & 7) * 8;
    float qf[4][8];
#pragma unroll
    for (int cq = 0; cq < 4; ++cq) {
      bf16x8 q8 = *(const bf16x8*)&Qb[((size_t)(bh * 4 + cq) * 224 + l0 + lq) * 64 + d0];
#pragma unroll
      for (int j = 0; j < 8; ++j) qf[cq][j] = b2f((u16)q8[j]);
    }
    float wv_[16];
#pragma unroll
    for (int c = 0; c < 16; ++c) wv_[c] = wg[lq * 16 + c];
#pragma unroll
    for (int ck = 0; ck < 4; ++ck) {
      float a[8];
#pragma unroll
      for (int j = 0; j < 8; ++j)
        a[j] = wv_[0 * 4 + ck] * qf[0][j] + wv_[1 * 4 + ck] * qf[1][j] +
               wv_[2 * 4 + ck] * qf[2][j] + wv_[3 * 4 + ck] * qf[3][j];
#pragma unroll
      for (int p = 0; p < 4; ++p) {
        unsigned int pk = f2b(a[2 * p]) | ((unsigned int)f2b(a[2 * p + 1]) << 16);
        *(unsigned int*)&qwpb[lq * 264 + ck * 64 + d0 + 2 * p] = pk;
      }
    }
  }
  __syncthreads();

  // ---- scores into registers: wave handles m-tiles wv+4q (q=0..3, mt<13)
  f32x4 s0r[4], s1r[4];
#pragma unroll
  for (int q = 0; q < 4; ++q) {
    s0r[q] = (f32x4){0.f, 0.f, 0.f, 0.f};
    s1r[q] = (f32x4){0.f, 0.f, 0.f, 0.f};
  }
#pragma unroll
  for (int q = 0; q < 4; ++q) {
    const int mt = wv + q * 4;
    if (mt < 13) {
      f32x4 sc0 = {0.f, 0.f, 0.f, 0.f}, sc1 = {0.f, 0.f, 0.f, 0.f};
#pragma unroll
      for (int ks = 0; ks < 8; ++ks) {
        int ck = ks >> 1, dd = (ks & 1) * 32 + lk8 * 8;
        const u16* Km = Kb + (size_t)(bh * 4 + ck) * 208 * 64;
        bf16x8 bK = *(const bf16x8*)&Km[(mt * 16 + lrow) * 64 + dd];
        bf16x8 a0 = *(const bf16x8*)&qwpb[lrow * 264 + ck * 64 + dd];
        bf16x8 a1 = *(const bf16x8*)&qwpb[(16 + lrow) * 264 + ck * 64 + dd];
        sc0 = __builtin_amdgcn_mfma_f32_16x16x32_bf16(a0, bK, sc0, 0, 0, 0);
        sc1 = __builtin_amdgcn_mfma_f32_16x16x32_bf16(a1, bK, sc1, 0, 0, 0);
      }
      s0r[q] = sc0; s1r[q] = sc1;
    }
  }

  // ---- register row-softmax.  lane's value (q,j,hh): row la=lk8*4+j (+16hh),
  // col m = (wv+4q)*16 + lrow.
  float e0[4][4], e1[4][4];
#pragma unroll
  for (int q = 0; q < 4; ++q) {
    const int mt = wv + q * 4;
    const int m = mt * 16 + lrow;
#pragma unroll
    for (int j = 0; j < 4; ++j) {
      if (mt < 13 && m < 200) {
        int gla = l0 + lk8 * 4 + j;      if (gla > 199) gla = 199;
        int glb = l0 + 16 + lk8 * 4 + j; if (glb > 199) glb = 199;
        e0[q][j] = s0r[q][j] * SCALE_ + mask[(size_t)gla * 200 + m];
        e1[q][j] = s1r[q][j] * SCALE_ + mask[(size_t)glb * 200 + m];
      } else {
        e0[q][j] = -3.0e38f;
        e1[q][j] = -3.0e38f;
      }
    }
  }
  float M0[4], M1[4];
#pragma unroll
  for (int j = 0; j < 4; ++j) {
    M0[j] = fmaxf(fmaxf(e0[0][j], e0[1][j]), fmaxf(e0[2][j], e0[3][j]));
    M1[j] = fmaxf(fmaxf(e1[0][j], e1[1][j]), fmaxf(e1[2][j], e1[3][j]));
  }
#pragma unroll
  for (int o = 8; o >= 1; o >>= 1)
#pragma unroll
    for (int j = 0; j < 4; ++j) {
      M0[j] = fmaxf(M0[j], __shfl_xor(M0[j], o));
      M1[j] = fmaxf(M1[j], __shfl_xor(M1[j], o));
    }
  if (lrow == 0) {
#pragma unroll
    for (int j = 0; j < 4; ++j) {
      redm[lk8 * 4 + j][wv] = M0[j];
      redm[16 + lk8 * 4 + j][wv] = M1[j];
    }
  }
  __syncthreads();
#pragma unroll
  for (int j = 0; j < 4; ++j) {
    int la = lk8 * 4 + j;
    M0[j] = fmaxf(fmaxf(redm[la][0], redm[la][1]), fmaxf(redm[la][2], redm[la][3]));
    M1[j] = fmaxf(fmaxf(redm[16 + la][0], redm[16 + la][1]),
                  fmaxf(redm[16 + la][2], redm[16 + la][3]));
  }
  float S0[4] = {0.f, 0.f, 0.f, 0.f}, S1[4] = {0.f, 0.f, 0.f, 0.f};
#pragma unroll
  for (int q = 0; q < 4; ++q)
#pragma unroll
    for (int j = 0; j < 4; ++j) {
      e0[q][j] = __expf(e0[q][j] - M0[j]);
      e1[q][j] = __expf(e1[q][j] - M1[j]);
      S0[j] += e0[q][j];
      S1[j] += e1[q][j];
    }
#pragma unroll
  for (int o = 8; o >= 1; o >>= 1)
#pragma unroll
    for (int j = 0; j < 4; ++j) {
      S0[j] += __shfl_xor(S0[j], o);
      S1[j] += __shfl_xor(S1[j], o);
    }
  if (lrow == 0) {
#pragma unroll
    for (int j = 0; j < 4; ++j) {
      reds[lk8 * 4 + j][wv] = S0[j];
      reds[16 + lk8 * 4 + j][wv] = S1[j];
    }
  }
  __syncthreads();   // also: all qwpb reads (scores) complete past this point
  float R0[4], R1[4];
#pragma unroll
  for (int j = 0; j < 4; ++j) {
    int la = lk8 * 4 + j;
    R0[j] = 1.f / (reds[la][0] + reds[la][1] + reds[la][2] + reds[la][3]);
    R1[j] = 1.f / (reds[16 + la][0] + reds[16 + la][1] +
                   reds[16 + la][2] + reds[16 + la][3]);
  }

  // ---- probs bf16 into pb (overlays qw region)
  u16* pb = qwpb;
  for (int idx = tid; idx < 768; idx += 256) {     // zero cols 208..231
    int l = idx / 24, mm = idx % 24;
    pb[l * 232 + 208 + mm] = 0;
  }
#pragma unroll
  for (int q = 0; q < 4; ++q) {
    const int mt = wv + q * 4;
    if (mt < 13) {
      const int m = mt * 16 + lrow;
#pragma unroll
      for (int j = 0; j < 4; ++j) {
        pb[(lk8 * 4 + j) * 232 + m] = f2b(e0[q][j] * R0[j]);
        pb[(16 + lk8 * 4 + j) * 232 + m] = f2b(e1[q][j] * R1[j]);
      }
    }
  }
  __syncthreads();

  // ---- PV: wave owns d-tile wv (16 d).  K = 224 (7 steps), pad probs = 0.
  {
    const u16* Vb = Vt + (size_t)bh * 64 * 224;
    f32x4 pc0 = {0.f, 0.f, 0.f, 0.f}, pc1 = {0.f, 0.f, 0.f, 0.f};
#pragma unroll
    for (int ks = 0; ks < 7; ++ks) {
      int mm = ks * 32 + lk8 * 8;
      bf16x8 a0 = *(const bf16x8*)&pb[lrow * 232 + mm];
      bf16x8 a1 = *(const bf16x8*)&pb[(16 + lrow) * 232 + mm];
      bf16x8 bV = *(const bf16x8*)&Vb[(wv * 16 + lrow) * 224 + mm];
      pc0 = __builtin_amdgcn_mfma_f32_16x16x32_bf16(a0, bV, pc0, 0, 0, 0);
      pc1 = __builtin_amdgcn_mfma_f32_16x16x32_bf16(a1, bV, pc1, 0, 0, 0);
    }
#pragma unroll
    for (int j = 0; j < 4; ++j) {
      int la = lk8 * 4 + j, lb = 16 + lk8 * 4 + j;
      int gla = l0 + la, glb = l0 + lb;
      int d = h * 64 + wv * 16 + lrow;
      if (gla < 200) Ctxb[((size_t)b * 200 + gla) * 256 + d] = f2b(pc0[j]);
      if (glb < 200) Ctxb[((size_t)b * 200 + glb) * 256 + d] = f2b(pc1[j]);
    }
  }
}

// ---------------------------------------------------------------------------
// Kernel 5: out-proj via MFMA + residual + LayerNorm.  32 rows per block,
// grid 200 (R13 config; 16-row/400-block split measured slower in R15).
// ---------------------------------------------------------------------------
__global__ __launch_bounds__(256) void out_ln_kernel(
    const u16* __restrict__ Ctxb, const u16* __restrict__ WdT,
    const float* __restrict__ bd, const float* __restrict__ input,
    const float* __restrict__ gamma, const float* __restrict__ beta,
    float* __restrict__ out) {
  const int row0 = blockIdx.x * 32;
  const int tid = threadIdx.x;
  const int wv = tid >> 6, ln = tid & 63;
  const int lrow = ln & 15, lk8 = ln >> 4;

  __shared__ float redA[32][65];
  __shared__ float redB[32][65];
  __shared__ float mus[32], rsd[32];

  f32x4 c[2][4];
#pragma unroll
  for (int mt = 0; mt < 2; ++mt)
#pragma unroll
    for (int nt = 0; nt < 4; ++nt) c[mt][nt] = (f32x4){0.f, 0.f, 0.f, 0.f};

#pragma unroll
  for (int ks = 0; ks < 8; ++ks) {
    bf16x8 a[2], bfr[4];
#pragma unroll
    for (int mt = 0; mt < 2; ++mt)
      a[mt] = *(const bf16x8*)&Ctxb[(size_t)(row0 + mt * 16 + lrow) * 256 + ks * 32 + lk8 * 8];
#pragma unroll
    for (int nt = 0; nt < 4; ++nt)
      bfr[nt] = *(const bf16x8*)&WdT[(size_t)(wv * 64 + nt * 16 + lrow) * 256 + ks * 32 + lk8 * 8];
#pragma unroll
    for (int mt = 0; mt < 2; ++mt)
#pragma unroll
      for (int nt = 0; nt < 4; ++nt)
        c[mt][nt] = __builtin_amdgcn_mfma_f32_16x16x32_bf16(a[mt], bfr[nt], c[mt][nt], 0, 0, 0);
  }

  float s1[2][4], s2[2][4];
#pragma unroll
  for (int mt = 0; mt < 2; ++mt)
#pragma unroll
    for (int j = 0; j < 4; ++j) { s1[mt][j] = 0.f; s2[mt][j] = 0.f; }

#pragma unroll
  for (int nt = 0; nt < 4; ++nt) {
    int n = wv * 64 + nt * 16 + lrow;
    float bdn = bd[n];
#pragma unroll
    for (int mt = 0; mt < 2; ++mt) {
      int mbase = row0 + mt * 16 + lk8 * 4;
#pragma unroll
      for (int j = 0; j < 4; ++j) {
        float x = c[mt][nt][j] + bdn + input[(size_t)(mbase + j) * 256 + n];
        c[mt][nt][j] = x;
        s1[mt][j] += x;
        s2[mt][j] += x * x;
      }
    }
  }
#pragma unroll
  for (int mt = 0; mt < 2; ++mt)
#pragma unroll
    for (int j = 0; j < 4; ++j) {
      redA[mt * 16 + lk8 * 4 + j][wv * 16 + lrow] = s1[mt][j];
      redB[mt * 16 + lk8 * 4 + j][wv * 16 + lrow] = s2[mt][j];
    }
  __syncthreads();
  if (tid < 32) {
    float a = 0.f, b2 = 0.f;
#pragma unroll 8
    for (int i = 0; i < 64; ++i) { a += redA[tid][i]; b2 += redB[tid][i]; }
    float mu = a * (1.f / 256.f);
    float var = b2 * (1.f / 256.f) - mu * mu;
    mus[tid] = mu;
    rsd[tid] = rsqrtf(var + EPS_);
  }
  __syncthreads();
#pragma unroll
  for (int nt = 0; nt < 4; ++nt) {
    int n = wv * 64 + nt * 16 + lrow;
    float g = gamma[n], be = beta[n];
#pragma unroll
    for (int mt = 0; mt < 2; ++mt) {
#pragma unroll
      for (int j = 0; j < 4; ++j) {
        int r = mt * 16 + lk8 * 4 + j;
        out[(size_t)(row0 + r) * 256 + n] = (c[mt][nt][j] - mus[r]) * rsd[r] * g + be;
      }
    }
  }
}

// ---------------------------------------------------------------------------
extern "C" void kernel_launch(void* const* d_in, const int* in_sizes, int n_in,
                              void* d_out, int out_size, void* d_ws, size_t ws_size,
                              hipStream_t stream) {
  const float* input = (const float*)d_in[0];
  const float* attrt = (const float*)d_in[1];   // (F,B,L,1,H)
  const float* pos   = (const float*)d_in[2];
  const float* mask  = (const float*)d_in[3];
  const float* Wq  = (const float*)d_in[4];   const float* bq  = (const float*)d_in[5];
  const float* Wk  = (const float*)d_in[6];   const float* bk  = (const float*)d_in[7];
  const float* Wv  = (const float*)d_in[8];   const float* bv  = (const float*)d_in[9];
  const float* Wqp = (const float*)d_in[10];  const float* bqp = (const float*)d_in[11];
  const float* Wkp = (const float*)d_in[12];  const float* bkp = (const float*)d_in[13];
  const float* Wq_a = (const float*)d_in[16]; const float* bq_a = (const float*)d_in[17];
  const float* Wk_a = (const float*)d_in[18]; const float* bk_a = (const float*)d_in[19];
  const float* Wf1 = (const float*)d_in[22];  const float* bf1 = (const float*)d_in[23];
  const float* Wf2 = (const float*)d_in[24];
  const float* Wd  = (const float*)d_in[26];  const float* bd  = (const float*)d_in[27];
  const float* gamma = (const float*)d_in[28]; const float* beta = (const float*)d_in[29];

  const float* attr0 = attrt;
  const float* attr1 = attrt + (size_t)B_ * L_ * H_;

  u16* wsu  = (u16*)d_ws;
  u16* Xb   = wsu;                    // 6,553,600
  u16* Wb   = Xb + 6553600;           //   655,360 (10 x 256 x 256)
  u16* Wf1T = Wb + 655360;            //    46,592 (208 x 224)
  u16* Qb   = Wf1T + 46592;           // 7,340,032 (512 x 224 x 64)
  u16* Kb   = Qb + 7340032;           // 6,815,744 (512 x 208 x 64)
  u16* Ktd  = Kb + 6815744;           // 7,340,032 (512 x 64 x 224)
  u16* Vt   = Ktd + 7340032;          // 1,835,008 (128 x 64 x 224)
  u16* KWb  = Vt + 1835008;           // 8,388,608 (512 x 256 x 64)
  u16* Ctxb = KWb + 8388608;          // 1,638,400 (6400 x 256)

  PrepArgs pp;
  pp.X[0] = input; pp.X[1] = pos; pp.X[2] = attr0; pp.X[3] = attr1;
  pp.W[0] = Wq;  pp.W[1] = Wqp; pp.W[2] = Wq_a; pp.W[3] = Wq_a + 65536;
  pp.W[4] = Wk;  pp.W[5] = Wk_a; pp.W[6] = Wk_a + 65536; pp.W[7] = Wkp;
  pp.W[8] = Wv;  pp.W[9] = Wd;
  pp.Wf1 = Wf1;

  BiasArgs ba;
  ba.Bi[0] = bq;  ba.Bi[1] = bqp;  ba.Bi[2] = bq_a; ba.Bi[3] = bq_a + 256;
  ba.Bi[4] = bk;  ba.Bi[5] = bk_a; ba.Bi[6] = bk_a + 256; ba.Bi[7] = bkp;
  ba.Bi[8] = bv;

  prep_kernel<<<dim3(2048), dim3(256), 0, stream>>>(pp, Xb, Wb, Wf1T, Qb, Kb);
  proj_mfma<<<dim3(100, 9), dim3(256), 0, stream>>>(Xb, Wb, ba, Qb, Kb, Ktd, Vt);
  kw_mfma<<<dim3(512), dim3(256), 0, stream>>>(Wf1T, Ktd, KWb);
  fused_kernel<<<dim3(896), dim3(256), 0, stream>>>(Qb, Kb, KWb, Vt,
                                                    mask, bf1, Wf2, Ctxb);
  out_ln_kernel<<<dim3(200), dim3(256), 0, stream>>>(Ctxb, Wb + 9 * 65536, bd,
                                                     input, gamma, beta,
                                                     (float*)d_out);
}